// Round 6
// baseline (193.905 us; speedup 1.0000x reference)
//
#include <hip/hip_runtime.h>
#include <math.h>

#define NH 8
#define DHD 64
#define DMODEL 512
#define QB 16
#define SEQ 512
#define NROWS (QB*SEQ)      /* 8192 rows per input */
#define NHQ (NH*QB)         /* 128 (h,q) pairs */
#define KCOV ((float)((0.001/512.0)/(8.0+1e-8)))

typedef __attribute__((ext_vector_type(8))) short short8;      // 8 bf16 -> 4 VGPR
typedef __attribute__((ext_vector_type(8))) unsigned short ushort8v;
typedef __attribute__((ext_vector_type(4))) unsigned short ushort4v;
typedef __attribute__((ext_vector_type(4))) float f32x4;

__device__ __forceinline__ float bf2f(unsigned short u){
  union { unsigned int i; float f; } c; c.i = ((unsigned int)u)<<16; return c.f;
}
__device__ __forceinline__ unsigned short f2bf(float f){
  union { float f; unsigned int i; } c; c.f = f;
  unsigned int u = c.i;
  u += 0x7fffu + ((u>>16)&1u);   // RNE
  return (unsigned short)(u>>16);
}
__device__ __forceinline__ unsigned cvtpk(float a, float b){
  unsigned r; asm("v_cvt_pk_bf16_f32 %0, %1, %2" : "=v"(r) : "v"(a), "v"(b)); return r;
}
__device__ __forceinline__ float clampf(float x, float lo, float hi){ return fminf(fmaxf(x,lo),hi); }

__device__ __forceinline__ f32x4 MFMA(short8 a, short8 b, f32x4 c){
  return __builtin_amdgcn_mfma_f32_16x16x32_bf16(a, b, c, 0, 0, 0);
}
// swizzled-tile access: element (row, kbyte), rowbytes pitch, XOR-swizzle bits 4-6 by row&7
__device__ __forceinline__ short8 frag_ld(const unsigned short* T, int row, int rowbytes, int kbyte){
  int addr = row*rowbytes + (kbyte ^ ((row&7)<<4));
  return *reinterpret_cast<const short8*>(reinterpret_cast<const char*>(T) + addr);
}
__device__ __forceinline__ void tile_st16(unsigned short* T, int row, int rowbytes, int kbyte, ushort8v v){
  int addr = row*rowbytes + (kbyte ^ ((row&7)<<4));
  *reinterpret_cast<ushort8v*>(reinterpret_cast<char*>(T) + addr) = v;
}

// ---------------------------------------------------------------- P0: LN stats+apply (bf16 out) + weight convert
__global__ void __launch_bounds__(256) prep_kernel(
    const float* __restrict__ xq, const float* __restrict__ xk, const float* __restrict__ xv,
    const float* __restrict__ ln_g, const float* __restrict__ ln_b,
    const float* __restrict__ Wi, const float* __restrict__ Wo,
    unsigned short* __restrict__ xln,
    unsigned short* __restrict__ WiT, unsigned short* __restrict__ WoT)
{
  __shared__ float T[64][68];
  int b = blockIdx.x, t = threadIdx.x;
  if (b < 6144){
    int which = b >> 11, rowblk = b & 2047;
    const float* src = which==0 ? xq : (which==1 ? xk : xv);
    int w = t >> 6, lane = t & 63;
    int row = rowblk*4 + w;
    const float* x = src + (size_t)row*DMODEL;
    float4 v1 = *reinterpret_cast<const float4*>(&x[lane*8]);
    float4 v2 = *reinterpret_cast<const float4*>(&x[lane*8+4]);
    float s  = v1.x+v1.y+v1.z+v1.w + v2.x+v2.y+v2.z+v2.w;
    float ss = v1.x*v1.x+v1.y*v1.y+v1.z*v1.z+v1.w*v1.w
             + v2.x*v2.x+v2.y*v2.y+v2.z*v2.z+v2.w*v2.w;
    #pragma unroll
    for (int m=32; m>0; m>>=1){ s += __shfl_xor(s,m,64); ss += __shfl_xor(ss,m,64); }
    float m_ = s*(1.0f/DMODEL);
    float var = ss*(1.0f/DMODEL) - m_*m_;
    float r_ = rsqrtf(var + 1e-5f);
    float4 g1 = *reinterpret_cast<const float4*>(&ln_g[lane*8]);
    float4 g2 = *reinterpret_cast<const float4*>(&ln_g[lane*8+4]);
    float4 b1 = *reinterpret_cast<const float4*>(&ln_b[lane*8]);
    float4 b2 = *reinterpret_cast<const float4*>(&ln_b[lane*8+4]);
    ushort8v o;
    o[0]=f2bf((v1.x-m_)*r_*g1.x + b1.x);
    o[1]=f2bf((v1.y-m_)*r_*g1.y + b1.y);
    o[2]=f2bf((v1.z-m_)*r_*g1.z + b1.z);
    o[3]=f2bf((v1.w-m_)*r_*g1.w + b1.w);
    o[4]=f2bf((v2.x-m_)*r_*g2.x + b2.x);
    o[5]=f2bf((v2.y-m_)*r_*g2.y + b2.y);
    o[6]=f2bf((v2.z-m_)*r_*g2.z + b2.z);
    o[7]=f2bf((v2.w-m_)*r_*g2.w + b2.w);
    *reinterpret_cast<ushort8v*>(&xln[((size_t)which*NROWS + row)*DMODEL + lane*8]) = o;
  } else {
    int wb = b - 6144;
    const float* src = (wb>=64) ? Wo : Wi;
    unsigned short* dst = (wb>=64) ? WoT : WiT;
    int rc = wb & 63;
    int r0 = (rc>>3)*64, c0 = (rc&7)*64;
    for (int it=0; it<4; ++it){
      int idx = it*256+t, row = idx>>4, q = idx&15;
      float4 v = *reinterpret_cast<const float4*>(&src[(size_t)(r0+row)*DMODEL + c0 + q*4]);
      T[row][q*4+0]=v.x; T[row][q*4+1]=v.y; T[row][q*4+2]=v.z; T[row][q*4+3]=v.w;
    }
    __syncthreads();
    for (int it=0; it<4; ++it){
      int idx = it*256+t, oc = idx>>4, q = idx&15;
      ushort4v o;
      o[0]=f2bf(T[q*4+0][oc]); o[1]=f2bf(T[q*4+1][oc]);
      o[2]=f2bf(T[q*4+2][oc]); o[3]=f2bf(T[q*4+3][oc]);
      *reinterpret_cast<ushort4v*>(&dst[(size_t)(c0+oc)*DMODEL + r0 + q*4]) = o;
    }
  }
}

// ---------------------------------------------------------------- K1b: projection GEMM (pure bf16 MFMA) + row stats
__global__ void __launch_bounds__(256) proj_mfma_kernel(
    const unsigned short* __restrict__ xln,
    const unsigned short* __restrict__ WiT,
    unsigned short* __restrict__ fq, unsigned short* __restrict__ fk, unsigned short* __restrict__ fvT,
    float* __restrict__ aqA, float* __restrict__ i1qA,
    float* __restrict__ rskA, float* __restrict__ i1kA)
{
  int which = blockIdx.z;
  const unsigned short* src = xln + (size_t)which*NROWS*DMODEL;
  int r0 = blockIdx.x*128;   // x rows (n-dim)
  int c0 = blockIdx.y*128;   // output cols (head*64+d dim)
  __shared__ unsigned short XT[128*64];
  __shared__ unsigned short WT[128*64];
  int t = threadIdx.x;
  int w=t>>6, lane=t&63, l16=lane&15, lh=lane>>4;
  f32x4 acc[4][4];
  #pragma unroll
  for(int i=0;i<4;i++){ for(int j=0;j<4;j++) acc[i][j]=(f32x4){0.f,0.f,0.f,0.f}; }
  for (int k0=0;k0<DMODEL;k0+=64){
    __syncthreads();
    for (int it=0; it<4; ++it){
      int idx=it*256+t, row=idx>>3, q=idx&7;
      ushort8v v = *reinterpret_cast<const ushort8v*>(&src[(size_t)(r0+row)*DMODEL + k0 + q*8]);
      tile_st16(XT, row, 128, q*16, v);
    }
    for (int it=0; it<4; ++it){
      int idx=it*256+t, row=idx>>3, q=idx&7;
      ushort8v v = *reinterpret_cast<const ushort8v*>(&WiT[(size_t)(c0+row)*DMODEL + k0 + q*8]);
      tile_st16(WT, row, 128, q*16, v);
    }
    __syncthreads();
    if (which<2){
      int dr=(w&1)*64, nc=(w>>1)*64;
      #pragma unroll
      for (int ks=0; ks<2; ++ks){
        int kb = lh*16 + ks*64;
        short8 a[4], b[4];
        #pragma unroll
        for (int i=0;i<4;i++) a[i] = frag_ld(WT, dr+i*16+l16, 128, kb);
        #pragma unroll
        for (int j=0;j<4;j++) b[j] = frag_ld(XT, nc+j*16+l16, 128, kb);
        #pragma unroll
        for (int i=0;i<4;i++){
          #pragma unroll
          for (int j=0;j<4;j++) acc[i][j]=MFMA(a[i],b[j],acc[i][j]);
        }
      }
    } else {
      int nr=(w>>1)*64, dc=(w&1)*64;
      #pragma unroll
      for (int ks=0; ks<2; ++ks){
        int kb = lh*16 + ks*64;
        short8 a[4], b[4];
        #pragma unroll
        for (int i=0;i<4;i++) a[i] = frag_ld(XT, nr+i*16+l16, 128, kb);
        #pragma unroll
        for (int j=0;j<4;j++) b[j] = frag_ld(WT, dc+j*16+l16, 128, kb);
        #pragma unroll
        for (int i=0;i<4;i++){
          #pragma unroll
          for (int j=0;j<4;j++) acc[i][j]=MFMA(a[i],b[j],acc[i][j]);
        }
      }
    }
  }
  if (which<2){
    unsigned short* dst = which ? fk : fq;
    int dr=(w&1)*64, nc=(w>>1)*64;
    #pragma unroll
    for (int i=0;i<4;i++){
      #pragma unroll
      for (int j=0;j<4;j++){
        int cl = c0 + dr + i*16 + lh*4;
        int ng = r0 + nc + j*16 + l16;
        int head = cl>>6, dd = cl&63;
        int hq = head*QB + (ng>>9);
        int n = ng&511;
        ushort4v o;
        o[0]=f2bf(acc[i][j][0]); o[1]=f2bf(acc[i][j][1]);
        o[2]=f2bf(acc[i][j][2]); o[3]=f2bf(acc[i][j][3]);
        *reinterpret_cast<ushort4v*>(&dst[((size_t)hq*SEQ+n)*DHD + dd]) = o;
      }
    }
    // fused row stats: sum_d f, sum_d f^2 for this wave's head
    int head = (c0>>6) + (w&1);
    #pragma unroll
    for (int j=0;j<4;j++){
      float s=0.f, ss=0.f;
      #pragma unroll
      for (int i=0;i<4;i++){
        #pragma unroll
        for (int r=0;r<4;r++){ float x = acc[i][j][r]; s += x; ss = fmaf(x,x,ss); }
      }
      s += __shfl_xor(s,16,64); ss += __shfl_xor(ss,16,64);
      s += __shfl_xor(s,32,64); ss += __shfl_xor(ss,32,64);
      if (lh==0){
        int ng = r0 + nc + j*16 + l16;
        int hq = head*QB + (ng>>9);
        int n = ng&511;
        float nrm = sqrtf(ss);
        if (which==0){
          aqA[hq*SEQ+n]  = s*(1.0f/64.0f);
          i1qA[hq*SEQ+n] = 1.0f/(nrm+1e-8f);
        } else {
          rskA[hq*SEQ+n] = s;
          i1kA[hq*SEQ+n] = 1.0f/(nrm+1e-8f);
        }
      }
    }
  } else {
    int nr=(w>>1)*64, dc=(w&1)*64;
    #pragma unroll
    for (int i=0;i<4;i++){
      #pragma unroll
      for (int j=0;j<4;j++){
        int ngb = r0 + nr + i*16 + lh*4;
        int dg  = c0 + dc + j*16 + l16;
        int head = dg>>6, dd = dg&63;
        int hq = head*QB + (ngb>>9);
        int n = ngb&511;
        ushort4v o;
        o[0]=f2bf(acc[i][j][0]); o[1]=f2bf(acc[i][j][1]);
        o[2]=f2bf(acc[i][j][2]); o[3]=f2bf(acc[i][j][3]);
        *reinterpret_cast<ushort4v*>(&fvT[((size_t)hq*DHD+dd)*SEQ + n]) = o;
      }
    }
  }
}

// ---------------------------------------------------------------- S: full column stats (one block per hq,isk)
__global__ void __launch_bounds__(256) colstat_kernel(
    const unsigned short* __restrict__ fq, const unsigned short* __restrict__ fk,
    float* __restrict__ qgp, float* __restrict__ kgp, float* __restrict__ c2A)
{
  int hq = blockIdx.x, isk = blockIdx.y;
  const unsigned short* F = (isk ? fk : fq) + (size_t)hq*SEQ*DHD;
  int t = threadIdx.x, g = t&15, rg = t>>4;
  float acc0=0.f, acc1=0.f, acc2=0.f, acc3=0.f;
  #pragma unroll 4
  for (int i=0;i<32;i++){
    int r = rg + 16*i;
    ushort4v v = *reinterpret_cast<const ushort4v*>(&F[(size_t)r*DHD + g*4]);
    acc0+=bf2f(v[0]); acc1+=bf2f(v[1]); acc2+=bf2f(v[2]); acc3+=bf2f(v[3]);
  }
  __shared__ float sh[16][68];
  sh[rg][g*4+0]=acc0; sh[rg][g*4+1]=acc1; sh[rg][g*4+2]=acc2; sh[rg][g*4+3]=acc3;
  __syncthreads();
  if (t<64){
    float s=0.f;
    #pragma unroll
    for (int r=0;r<16;r++) s += sh[r][t];
    if (isk){
      kgp[hq*64+t]=s;
      float c = s*(1.0f/512.0f);
      #pragma unroll
      for (int m=32;m>0;m>>=1) c += __shfl_xor(c,m,64);
      if (t==0) c2A[hq]=c;
    } else {
      qgp[hq*64+t]=s;
    }
  }
}

// ---------------------------------------------------------------- M1: moments + rowmax + c1 (barrier-free main loop)
__global__ void __launch_bounds__(256,6) score_m1_kernel(
    const unsigned short* __restrict__ fq, const unsigned short* __restrict__ fk,
    const float* __restrict__ aqA, const float* __restrict__ i1qA,
    const float* __restrict__ rskA, const float* __restrict__ i1kA,
    const float* __restrict__ c2A, const float* __restrict__ kgp,
    float* __restrict__ c1A, float* __restrict__ rmaxcA, float* __restrict__ rmaxoA,
    float* __restrict__ momf, double* __restrict__ varp)
{
  int strip=blockIdx.x, q_=blockIdx.y, h=blockIdx.z;
  int hq=h*QB+q_, n0=strip*64;
  const unsigned short* Fq=fq+(size_t)hq*SEQ*DHD;
  const unsigned short* Fk=fk+(size_t)hq*SEQ*DHD;
  __shared__ float rskL[512], i1kL[512];
  __shared__ float red[256];
  __shared__ double dred[256];
  int t=threadIdx.x, w=t>>6, lane=t&63, l16=lane&15, lh=lane>>4;
  int n = n0 + w*16 + l16;
  for (int i=t;i<512;i+=256){ rskL[i]=rskA[hq*SEQ+i]; i1kL[i]=i1kA[hq*SEQ+i]; }
  float c2v = c2A[hq];
  float aqv = aqA[hq*SEQ+n];
  float iq1 = i1qA[hq*SEQ+n];
  short8 qa[2];
  #pragma unroll
  for (int ks=0;ks<2;ks++)
    qa[ks] = *reinterpret_cast<const short8*>(&Fq[(size_t)n*DHD + ks*32 + lh*8]);
  // c1[n] = fq[n] . (kgp/512)
  float c1v = 0.f;
  #pragma unroll
  for (int ks=0;ks<2;ks++){
    const float* bkp = &kgp[hq*64 + ks*32 + lh*8];
    float4 b0 = *reinterpret_cast<const float4*>(bkp);
    float4 b1 = *reinterpret_cast<const float4*>(bkp+4);
    float bb[8] = {b0.x,b0.y,b0.z,b0.w,b1.x,b1.y,b1.z,b1.w};
    #pragma unroll
    for (int i=0;i<8;i++) c1v = fmaf(bf2f((unsigned short)qa[ks][i]), bb[i], c1v);
  }
  c1v *= (1.0f/512.0f);
  c1v += __shfl_xor(c1v,16,64);
  c1v += __shfl_xor(c1v,32,64);
  if (lane<16) c1A[hq*SEQ+n] = c1v;
  float c1x = KCOV*(c1v - aqv*c2v);
  float aqx = KCOV*aqv;
  __syncthreads();   // rskL/i1kL visible
  float sc=0.f,sc2=0.f,so=0.f,so2=0.f,sco=0.f;
  float rc=0.f, ro=0.f, rm=0.f, rmc=-1e30f, rmo=-1e30f;
  for (int mc=0;mc<8;mc++){
    int mb = mc*64;
    f32x4 acc[4];
    #pragma unroll
    for (int mf=0;mf<4;mf++) acc[mf]=(f32x4){0.f,0.f,0.f,0.f};
    #pragma unroll
    for (int mf=0;mf<4;mf++){
      #pragma unroll
      for (int ks=0;ks<2;ks++){
        short8 kf = *reinterpret_cast<const short8*>(
            &Fk[(size_t)(mb+mf*16+l16)*DHD + ks*32 + lh*8]);
        acc[mf] = MFMA(kf, qa[ks], acc[mf]);
      }
    }
    #pragma unroll
    for (int mf=0;mf<4;mf++){
      int ml = mb + mf*16 + lh*4;
      float4 rsk4 = *reinterpret_cast<const float4*>(&rskL[ml]);
      float4 i1k4 = *reinterpret_cast<const float4*>(&i1kL[ml]);
      float rk[4]={rsk4.x,rsk4.y,rsk4.z,rsk4.w};
      float ik[4]={i1k4.x,i1k4.y,i1k4.z,i1k4.w};
      #pragma unroll
      for (int r=0;r<4;r++){
        float S = acc[mf][r];
        float cosv = clampf(S*iq1*ik[r], -0.99f, 0.99f);
        float u = fmaf(KCOV, S, -c1x);
        float covv = fmaf(-aqx, rk[r], u);
        covv = clampf(covv, -10.0f, 10.0f);
        float marg = clampf(0.01f - cosv, 0.0f, 2.0f);
        sc += cosv; sc2 = fmaf(cosv,cosv,sc2);
        so += covv; so2 = fmaf(covv,covv,so2);
        sco = fmaf(cosv,covv,sco);
        rc += cosv; ro += covv; rm += marg;
        rmc = fmaxf(rmc, cosv); rmo = fmaxf(rmo, covv);
      }
    }
  }
  // row reductions across lh (lanes sharing l16)
  rc += __shfl_xor(rc,16,64); rc += __shfl_xor(rc,32,64);
  ro += __shfl_xor(ro,16,64); ro += __shfl_xor(ro,32,64);
  rm += __shfl_xor(rm,16,64); rm += __shfl_xor(rm,32,64);
  rmc = fmaxf(rmc, __shfl_xor(rmc,16,64)); rmc = fmaxf(rmc, __shfl_xor(rmc,32,64));
  rmo = fmaxf(rmo, __shfl_xor(rmo,16,64)); rmo = fmaxf(rmo, __shfl_xor(rmo,32,64));
  if (lane<16){
    rmaxcA[hq*SEQ+n] = rmc;
    rmaxoA[hq*SEQ+n] = rmo;
  }
  double vm=0.0, vm2=0.0, vmc=0.0, vmo=0.0;
  if (lane<16){
    float mm = rm*(1.0f/512.0f);
    vm  = (double)mm;
    vm2 = (double)mm*(double)mm;
    vmc = (double)mm*(double)rc;
    vmo = (double)mm*(double)ro;
  }
  float fs[5]={sc,sc2,so,so2,sco};
  for (int c=0;c<5;c++){
    __syncthreads();
    red[t]=fs[c]; __syncthreads();
    for (int o=128;o>0;o>>=1){ if (t<o) red[t]+=red[t+o]; __syncthreads(); }
    if (t==0) momf[(size_t)(hq*8+strip)*5 + c] = red[0];
  }
  double ds[4]={vm,vm2,vmc,vmo};
  for (int c=0;c<4;c++){
    __syncthreads();
    dred[t]=ds[c]; __syncthreads();
    for (int o=128;o>0;o>>=1){ if (t<o) dred[t]+=dred[t+o]; __syncthreads(); }
    if (t==0) varp[(size_t)(hq*8+strip)*4 + c] = dred[0];
  }
}

// ---------------------------------------------------------------- F: MLP + stds + mix params
__global__ void __launch_bounds__(256) finalize_kernel(
    const float* __restrict__ qgp, const float* __restrict__ kgp,
    const float* __restrict__ wp1w, const float* __restrict__ wp1b,
    const float* __restrict__ wplg, const float* __restrict__ wplb,
    const float* __restrict__ wp2w, const float* __restrict__ wp2b,
    const float* __restrict__ wp3w, const float* __restrict__ wp3b,
    const float* __restrict__ temp,
    const float* __restrict__ momf, const double* __restrict__ varp,
    float* __restrict__ params)
{
  int t = threadIdx.x;
  __shared__ float feats[8][128];
  __shared__ float h1s[8][64];
  __shared__ float h2s[8][32];
  __shared__ float wts[8][3];
  __shared__ double Sh[8][9];
  for (int idx=t; idx<512; idx+=256){
    int h = idx>>6, d = idx&63;
    float s1=0, s2=0;
    for (int qq=0; qq<QB; qq++){ s1 += qgp[(h*QB+qq)*64+d]; s2 += kgp[(h*QB+qq)*64+d]; }
    feats[h][d]    = s1*(1.0f/8192.0f);
    feats[h][64+d] = s2*(1.0f/8192.0f);
  }
  __syncthreads();
  int w = t>>6, j = t&63;
  for (int pp=0; pp<2; pp++){
    int h = w + pp*4;
    float acc = wp1b[j];
    for (int k=0;k<128;k++) acc += feats[h][k]*wp1w[k*64+j];
    float s=acc, s2=acc*acc;
    #pragma unroll
    for (int m=32;m>0;m>>=1){ s+=__shfl_xor(s,m,64); s2+=__shfl_xor(s2,m,64); }
    float mean = s*(1.0f/64.0f);
    float var  = s2*(1.0f/64.0f) - mean*mean;
    float xh = (acc-mean)*rsqrtf(var+1e-5f)*wplg[j] + wplb[j];
    h1s[h][j] = fmaxf(xh, 0.0f);
  }
  __syncthreads();
  {
    int h = t>>5, j2 = t&31;
    float acc = wp2b[j2];
    for (int k=0;k<64;k++) acc += h1s[h][k]*wp2w[k*32+j2];
    h2s[h][j2] = fmaxf(acc, 0.0f);
  }
  __syncthreads();
  if (t<8){
    int h = t;
    float z[3] = {wp3b[0], wp3b[1], wp3b[2]};
    for (int k=0;k<32;k++){
      float hv = h2s[h][k];
      z[0]+=hv*wp3w[k*3]; z[1]+=hv*wp3w[k*3+1]; z[2]+=hv*wp3w[k*3+2];
    }
    float mx = fmaxf(z[0], fmaxf(z[1], z[2]));
    float e0=expf(z[0]-mx), e1=expf(z[1]-mx), e2=expf(z[2]-mx);
    float inv = 1.0f/(e0+e1+e2);
    float l0=e0*inv, l1=e1*inv, l2=e2*inv;
    float tv = temp[0]; tv = fminf(fmaxf(tv, 0.1f), 20.0f);
    float y0=l0/tv, y1=l1/tv, y2=l2/tv;
    float mx2 = fmaxf(y0, fmaxf(y1, y2));
    float f0=expf(y0-mx2), f1=expf(y1-mx2), f2=expf(y2-mx2);
    float inv2 = 1.0f/(f0+f1+f2);
    wts[h][0]=f0*inv2; wts[h][1]=f1*inv2; wts[h][2]=f2*inv2;
  }
  __syncthreads();
  if (t<40){
    int h = t/5, c = t%5;
    double s = 0;
    for (int e=0; e<128; e++) s += (double)momf[(size_t)(h*128+e)*5 + c];
    Sh[h][c] = s;
  }
  __syncthreads();
  if (t<32){
    int h = t>>2, c = t&3;
    double s = 0;
    for (int e=0; e<128; e++) s += varp[(size_t)(h*128+e)*4 + c];
    Sh[h][5+c] = s;
  }
  __syncthreads();
  if (t==0){
    const double Ntot = 33554432.0;
    double T1c=0,T2c=0,T1o=0,T2o=0,T1v=0,T2v=0;
    for (int h=0;h<8;h++){
      T1c+=Sh[h][0]; T2c+=Sh[h][1]; T1o+=Sh[h][2]; T2o+=Sh[h][3];
      T1v+=512.0*Sh[h][5]; T2v+=512.0*Sh[h][6];
    }
    double stdc = sqrt(fmax((T2c - T1c*T1c/Ntot)/(Ntot-1.0), 0.0));
    double stdo = sqrt(fmax((T2o - T1o*T1o/Ntot)/(Ntot-1.0), 0.0));
    double stdv = sqrt(fmax((T2v - T1v*T1v/Ntot)/(Ntot-1.0), 0.0));
    double ah[8], bh[8];
    double Sd1=0, Sd2=0;
    for (int h=0;h<8;h++){
      double a = (double)wts[h][0]/(stdc+1e-8);
      double b = (double)wts[h][1]*0.1/(stdo+1e-8);
      double c = (double)wts[h][2]*0.1/(stdv+1e-8);
      ah[h]=a; bh[h]=b;
      Sd1 += a*Sh[h][0] + b*Sh[h][2] + c*512.0*Sh[h][5];
      Sd2 += a*a*Sh[h][1] + b*b*Sh[h][3] + c*c*512.0*Sh[h][6]
           + 2.0*a*b*Sh[h][4] + 2.0*a*c*Sh[h][7] + 2.0*b*c*Sh[h][8];
    }
    double stdd = sqrt(fmax((Sd2 - Sd1*Sd1/Ntot)/(Ntot-1.0), 0.0));
    double att = 1.0 + 0.5*stdd;
    att = fmin(fmax(att, 0.5), 5.0);
    double scale = 1.0/att;
    for (int h=0;h<8;h++){
      params[h*2+0] = (float)(scale*ah[h]);
      params[h*2+1] = (float)(scale*bh[h]);
    }
  }
}

// ---------------------------------------------------------------- M2: fixed-max softmax + PV (barrier-free main loop)
__global__ void __launch_bounds__(256,6) attn_m2_kernel(
    const unsigned short* __restrict__ fq, const unsigned short* __restrict__ fk,
    const unsigned short* __restrict__ fvT,
    const float* __restrict__ aqA, const float* __restrict__ c1A, const float* __restrict__ i1qA,
    const float* __restrict__ rskA, const float* __restrict__ i1kA,
    const float* __restrict__ c2A, const float* __restrict__ params,
    const float* __restrict__ rmaxcA, const float* __restrict__ rmaxoA,
    unsigned short* __restrict__ attn_bf)
{
  int strip=blockIdx.x, q_=blockIdx.y, h=blockIdx.z;
  int hq=h*QB+q_, n0=strip*64;
  const unsigned short* Fq=fq+(size_t)hq*SEQ*DHD;
  const unsigned short* Fk=fk+(size_t)hq*SEQ*DHD;
  const unsigned short* FvT=fvT+(size_t)hq*DHD*SEQ;
  __shared__ unsigned short P[64*64];       // [n][m-half] bf16, pitch 128B (per-wave rows)
  __shared__ float rskL[512], i1kL[512];
  int t=threadIdx.x, w=t>>6, lane=t&63, l16=lane&15, lh=lane>>4;
  int n = n0 + w*16 + l16;
  for (int i=t;i<512;i+=256){ rskL[i]=rskA[hq*SEQ+i]; i1kL[i]=i1kA[hq*SEQ+i]; }
  float c2v=c2A[hq];
  float pa=params[h*2], pb=params[h*2+1];
  float aqv = aqA[hq*SEQ+n];
  float c1v = c1A[hq*SEQ+n];
  float iq1 = i1qA[hq*SEQ+n];
  float rmc = rmaxcA[hq*SEQ+n];
  float rmo = rmaxoA[hq*SEQ+n];
  float pbk = pb*KCOV;
  float ra  = pa*iq1;
  float bndc = 0.99f*pa;
  float rowc = -pbk*(c1v - aqv*c2v);
  float r3   = pbk*aqv;
  float Mrow = fmaf(pa, rmc, pb*rmo);
  short8 qa[2];
  #pragma unroll
  for (int ks=0;ks<2;ks++)
    qa[ks] = *reinterpret_cast<const short8*>(&Fq[(size_t)n*DHD + ks*32 + lh*8]);
  short8 ones;
  #pragma unroll
  for (int i=0;i<8;i++) ones[i] = (short)0x3F80;
  f32x4 accO[4];
  #pragma unroll
  for (int j=0;j<4;j++) accO[j]=(f32x4){0.f,0.f,0.f,0.f};
  f32x4 den = (f32x4){0.f,0.f,0.f,0.f};
  __syncthreads();   // rskL/i1kL visible
  int prow = w*16 + l16;
  for (int mc=0;mc<8;mc++){
    int mb = mc*64;
    // QK^T (swapped): acc rows = K rows m, cols = own n
    f32x4 acc[4];
    #pragma unroll
    for (int mf=0;mf<4;mf++) acc[mf]=(f32x4){0.f,0.f,0.f,0.f};
    #pragma unroll
    for (int mf=0;mf<4;mf++){
      #pragma unroll
      for (int ks=0;ks<2;ks++){
        short8 kf = *reinterpret_cast<const short8*>(
            &Fk[(size_t)(mb+mf*16+l16)*DHD + ks*32 + lh*8]);
        acc[mf] = MFMA(kf, qa[ks], acc[mf]);
      }
    }
    // transform + exp(logit - Mrow), write P[n][m] packed (wave-local)
    #pragma unroll
    for (int mf=0;mf<4;mf++){
      int ml = mb + mf*16 + lh*4;
      float4 rsk4 = *reinterpret_cast<const float4*>(&rskL[ml]);
      float4 i1k4 = *reinterpret_cast<const float4*>(&i1kL[ml]);
      float rk[4]={rsk4.x,rsk4.y,rsk4.z,rsk4.w};
      float ik[4]={i1k4.x,i1k4.y,i1k4.z,i1k4.w};
      #pragma unroll
      for (int r=0;r<4;r++){
        float S = acc[mf][r];
        float tt = S*ra; tt *= ik[r];
        float cc = clampf(tt, -bndc, bndc);
        float u = fmaf(pbk, S, rowc);
        float lin = fmaf(-r3, rk[r], u);
        acc[mf][r] = __expf(cc + lin - Mrow);
      }
      unsigned lo = cvtpk(acc[mf][0], acc[mf][1]);
      unsigned hi = cvtpk(acc[mf][2], acc[mf][3]);
      int pbyte = (mf*32 + lh*8) ^ ((prow&7)<<4);
      *reinterpret_cast<uint2*>(reinterpret_cast<char*>(P) + prow*128 + pbyte)
        = make_uint2(lo, hi);
    }
    // PV + denominator (wave-local P rows; in-wave LDS ordering suffices)
    #pragma unroll
    for (int ks=0;ks<2;ks++){
      short8 pfrag = frag_ld(P, prow, 128, lh*16 + ks*64);
      #pragma unroll
      for (int dcf=0;dcf<4;dcf++){
        short8 vb = *reinterpret_cast<const short8*>(
            &FvT[(size_t)(dcf*16+l16)*SEQ + mb + ks*32 + lh*8]);
        accO[dcf] = MFMA(pfrag, vb, accO[dcf]);
      }
      den = MFMA(pfrag, ones, den);
    }
  }
  // epilogue: normalize, bounce through P, coalesced store
  f32x4 invD;
  #pragma unroll
  for (int r=0;r<4;r++) invD[r] = 1.0f/den[r];
  #pragma unroll
  for (int dcf=0;dcf<4;dcf++){
    #pragma unroll
    for (int r=0;r<4;r++){
      int row = w*16 + lh*4 + r;
      int col = dcf*16 + l16;
      int addr = row*128 + ((col*2) ^ ((row&7)<<4));
      *reinterpret_cast<unsigned short*>(reinterpret_cast<char*>(P) + addr)
        = f2bf(accO[dcf][r]*invD[r]);
    }
  }
  __syncthreads();
  for (int it=0; it<2; ++it){
    int idx = it*256 + t;
    int row = idx>>3, c = idx&7;
    int addr = row*128 + ((c*16) ^ ((row&7)<<4));
    ushort8v vv = *reinterpret_cast<ushort8v*>(reinterpret_cast<char*>(P) + addr);
    *reinterpret_cast<ushort8v*>(
      &attn_bf[(size_t)(q_*SEQ + n0 + row)*DMODEL + h*DHD + c*8]) = vv;
  }
}

// ---------------------------------------------------------------- KO: output projection (MFMA)
__global__ void __launch_bounds__(256) out_mfma_kernel(
    const unsigned short* __restrict__ attn_bf, const unsigned short* __restrict__ WoT,
    const float* __restrict__ bias, float* __restrict__ out)
{
  int r0=blockIdx.x*128;
  int c0=blockIdx.y*128;
  __shared__ unsigned short AT[128*64];
  __shared__ unsigned short WT[128*64];
  int t=threadIdx.x, w=t>>6, lane=t&63, l16=lane&15, lh=lane>>4;
  f32x4 acc[4][4];
  #pragma unroll
  for(int i=0;i<4;i++){ for(int j=0;j<4;j++) acc[i][j]=(f32x4){0.f,0.f,0.f,0.f}; }
  for (int k0=0;k0<DMODEL;k0+=64){
    __syncthreads();
    for (int it=0; it<4; ++it){
      int idx=it*256+t, row=idx>>3, q=idx&7;
      ushort8v v = *reinterpret_cast<const ushort8v*>(&attn_bf[(size_t)(r0+row)*DMODEL + k0 + q*8]);
      tile_st16(AT, row, 128, q*16, v);
    }
    for (int it=0; it<4; ++it){
      int idx=it*256+t, row=idx>>3, q=idx&7;
      ushort8v v = *reinterpret_cast<const ushort8v*>(&WoT[(size_t)(c0+row)*DMODEL + k0 + q*8]);
      tile_st16(WT, row, 128, q*16, v);
    }
    __syncthreads();
    int nr=(w&1)*64, mr=(w>>1)*64;
    #pragma unroll
    for (int ks=0; ks<2; ++ks){
      int kb = lh*16 + ks*64;
      short8 a[4], b[4];
      #pragma unroll
      for (int i=0;i<4;i++) a[i] = frag_ld(WT, nr+i*16+l16, 128, kb);
      #pragma unroll
      for (int j=0;j<4;j++) b[j] = frag_ld(AT, mr+j*16+l16, 128, kb);
      #pragma unroll
      for (int i=0;i<4;i++){
        #pragma unroll
        for (int j=0;j<4;j++) acc[i][j]=MFMA(a[i],b[j],acc[i][j]);
      }
    }
  }
  #pragma unroll
  for (int i=0;i<4;i++){
    int nb = c0+(w&1)*64+i*16+lh*4;
    float4 b4 = *reinterpret_cast<const float4*>(&bias[nb]);
    #pragma unroll
    for (int j=0;j<4;j++){
      int mg = r0+(w>>1)*64+j*16+l16;
      f32x4 o = acc[i][j];
      o[0]+=b4.x; o[1]+=b4.y; o[2]+=b4.z; o[3]+=b4.w;
      *reinterpret_cast<f32x4*>(&out[(size_t)mg*DMODEL + nb]) = o;
    }
  }
}

// ----------------------------------------------------------------
extern "C" void kernel_launch(void* const* d_in, const int* in_sizes, int n_in,
                              void* d_out, int out_size, void* d_ws, size_t ws_size,
                              hipStream_t stream)
{
  (void)in_sizes; (void)n_in; (void)out_size; (void)ws_size;
  const float* q     = (const float*)d_in[0];
  const float* k     = (const float*)d_in[1];
  const float* v     = (const float*)d_in[2];
  const float* ln_g  = (const float*)d_in[3];
  const float* ln_b  = (const float*)d_in[4];
  const float* W_in  = (const float*)d_in[5];
  const float* wp1w  = (const float*)d_in[6];
  const float* wp1b  = (const float*)d_in[7];
  const float* wplg  = (const float*)d_in[8];
  const float* wplb  = (const float*)d_in[9];
  const float* wp2w  = (const float*)d_in[10];
  const float* wp2b  = (const float*)d_in[11];
  const float* wp3w  = (const float*)d_in[12];
  const float* wp3b  = (const float*)d_in[13];
  const float* temp  = (const float*)d_in[14];
  const float* W_out = (const float*)d_in[15];
  const float* b_out = (const float*)d_in[16];
  float* out = (float*)d_out;

  char* wsb = (char*)d_ws;
  size_t off = 0;
  auto alloc = [&](size_t bytes)->char*{
    char* p = wsb + off; off += (bytes + 255) & ~(size_t)255; return p;
  };
  unsigned short* xln    = (unsigned short*)alloc((size_t)3*NROWS*DMODEL*2);
  unsigned short* fq_b   = (unsigned short*)alloc((size_t)NHQ*SEQ*DHD*2);
  unsigned short* fk_b   = (unsigned short*)alloc((size_t)NHQ*SEQ*DHD*2);
  unsigned short* fvT_b  = (unsigned short*)alloc((size_t)NHQ*SEQ*DHD*2);
  unsigned short* attn_b = (unsigned short*)alloc((size_t)NROWS*DMODEL*2);
  unsigned short* WiT    = (unsigned short*)alloc((size_t)DMODEL*DMODEL*2);
  unsigned short* WoT    = (unsigned short*)alloc((size_t)DMODEL*DMODEL*2);
  float* aqA    = (float*)alloc(NHQ*SEQ*4);
  float* c1A    = (float*)alloc(NHQ*SEQ*4);
  float* i1qA   = (float*)alloc(NHQ*SEQ*4);
  float* rskA   = (float*)alloc(NHQ*SEQ*4);
  float* i1kA   = (float*)alloc(NHQ*SEQ*4);
  float* rmaxcA = (float*)alloc(NHQ*SEQ*4);
  float* rmaxoA = (float*)alloc(NHQ*SEQ*4);
  float* c2A    = (float*)alloc(NHQ*4);
  float* qgp    = (float*)alloc(NHQ*64*4);
  float* kgp    = (float*)alloc(NHQ*64*4);
  float* momf   = (float*)alloc((size_t)NHQ*8*5*4);
  double* varp  = (double*)alloc((size_t)NHQ*8*4*8);
  float* params = (float*)alloc(64);

  prep_kernel<<<6272, 256, 0, stream>>>(q, k, v, ln_g, ln_b, W_in, W_out, xln, WiT, WoT);
  proj_mfma_kernel<<<dim3(64,4,3), 256, 0, stream>>>(xln, WiT, fq_b, fk_b, fvT_b,
                                                     aqA, i1qA, rskA, i1kA);
  colstat_kernel<<<dim3(NHQ, 2), 256, 0, stream>>>(fq_b, fk_b, qgp, kgp, c2A);
  score_m1_kernel<<<dim3(8, QB, NH), 256, 0, stream>>>(fq_b, fk_b, aqA, i1qA, rskA, i1kA,
                                                       c2A, kgp, c1A, rmaxcA, rmaxoA, momf, varp);
  finalize_kernel<<<1, 256, 0, stream>>>(qgp, kgp, wp1w, wp1b, wplg, wplb, wp2w, wp2b,
                                         wp3w, wp3b, temp, momf, varp, params);
  attn_m2_kernel<<<dim3(8, QB, NH), 256, 0, stream>>>(fq_b, fk_b, fvT_b, aqA, c1A, i1qA,
                                                      rskA, i1kA, c2A, params, rmaxcA, rmaxoA, attn_b);
  out_mfma_kernel<<<dim3(64,4), 256, 0, stream>>>(attn_b, WoT, b_out, out);
}

// Round 7
// 163.202 us; speedup vs baseline: 1.1881x; 1.1881x over previous
//
#include <hip/hip_runtime.h>
#include <math.h>

#define NH 8
#define DHD 64
#define DMODEL 512
#define QB 16
#define SEQ 512
#define NROWS (QB*SEQ)      /* 8192 rows per input */
#define NHQ (NH*QB)         /* 128 (h,q) pairs */
#define KCOV ((float)((0.001/512.0)/(8.0+1e-8)))

typedef __attribute__((ext_vector_type(8))) short short8;      // 8 bf16 -> 4 VGPR
typedef __attribute__((ext_vector_type(8))) unsigned short ushort8v;
typedef __attribute__((ext_vector_type(4))) unsigned short ushort4v;
typedef __attribute__((ext_vector_type(4))) float f32x4;

__device__ __forceinline__ float bf2f(unsigned short u){
  union { unsigned int i; float f; } c; c.i = ((unsigned int)u)<<16; return c.f;
}
__device__ __forceinline__ unsigned short f2bf(float f){
  union { float f; unsigned int i; } c; c.f = f;
  unsigned int u = c.i;
  u += 0x7fffu + ((u>>16)&1u);   // RNE
  return (unsigned short)(u>>16);
}
__device__ __forceinline__ unsigned cvtpk(float a, float b){
  unsigned r; asm("v_cvt_pk_bf16_f32 %0, %1, %2" : "=v"(r) : "v"(a), "v"(b)); return r;
}
__device__ __forceinline__ float clampf(float x, float lo, float hi){ return fminf(fmaxf(x,lo),hi); }

__device__ __forceinline__ f32x4 MFMA(short8 a, short8 b, f32x4 c){
  return __builtin_amdgcn_mfma_f32_16x16x32_bf16(a, b, c, 0, 0, 0);
}
// swizzled-tile access: element (row, kbyte), rowbytes pitch, XOR-swizzle bits 4-6 by row&7
__device__ __forceinline__ short8 frag_ld(const unsigned short* T, int row, int rowbytes, int kbyte){
  int addr = row*rowbytes + (kbyte ^ ((row&7)<<4));
  return *reinterpret_cast<const short8*>(reinterpret_cast<const char*>(T) + addr);
}
__device__ __forceinline__ void tile_st16(unsigned short* T, int row, int rowbytes, int kbyte, ushort8v v){
  int addr = row*rowbytes + (kbyte ^ ((row&7)<<4));
  *reinterpret_cast<ushort8v*>(reinterpret_cast<char*>(T) + addr) = v;
}

// ---------------------------------------------------------------- P0: LN stats+apply (bf16 out) + weight convert
__global__ void __launch_bounds__(256) prep_kernel(
    const float* __restrict__ xq, const float* __restrict__ xk, const float* __restrict__ xv,
    const float* __restrict__ ln_g, const float* __restrict__ ln_b,
    const float* __restrict__ Wi, const float* __restrict__ Wo,
    unsigned short* __restrict__ xln,
    unsigned short* __restrict__ WiT, unsigned short* __restrict__ WoT)
{
  __shared__ float T[64][68];
  int b = blockIdx.x, t = threadIdx.x;
  if (b < 6144){
    int which = b >> 11, rowblk = b & 2047;
    const float* src = which==0 ? xq : (which==1 ? xk : xv);
    int w = t >> 6, lane = t & 63;
    int row = rowblk*4 + w;
    const float* x = src + (size_t)row*DMODEL;
    float4 v1 = *reinterpret_cast<const float4*>(&x[lane*8]);
    float4 v2 = *reinterpret_cast<const float4*>(&x[lane*8+4]);
    float s  = v1.x+v1.y+v1.z+v1.w + v2.x+v2.y+v2.z+v2.w;
    float ss = v1.x*v1.x+v1.y*v1.y+v1.z*v1.z+v1.w*v1.w
             + v2.x*v2.x+v2.y*v2.y+v2.z*v2.z+v2.w*v2.w;
    #pragma unroll
    for (int m=32; m>0; m>>=1){ s += __shfl_xor(s,m,64); ss += __shfl_xor(ss,m,64); }
    float m_ = s*(1.0f/DMODEL);
    float var = ss*(1.0f/DMODEL) - m_*m_;
    float r_ = rsqrtf(var + 1e-5f);
    float4 g1 = *reinterpret_cast<const float4*>(&ln_g[lane*8]);
    float4 g2 = *reinterpret_cast<const float4*>(&ln_g[lane*8+4]);
    float4 b1 = *reinterpret_cast<const float4*>(&ln_b[lane*8]);
    float4 b2 = *reinterpret_cast<const float4*>(&ln_b[lane*8+4]);
    ushort8v o;
    o[0]=f2bf((v1.x-m_)*r_*g1.x + b1.x);
    o[1]=f2bf((v1.y-m_)*r_*g1.y + b1.y);
    o[2]=f2bf((v1.z-m_)*r_*g1.z + b1.z);
    o[3]=f2bf((v1.w-m_)*r_*g1.w + b1.w);
    o[4]=f2bf((v2.x-m_)*r_*g2.x + b2.x);
    o[5]=f2bf((v2.y-m_)*r_*g2.y + b2.y);
    o[6]=f2bf((v2.z-m_)*r_*g2.z + b2.z);
    o[7]=f2bf((v2.w-m_)*r_*g2.w + b2.w);
    *reinterpret_cast<ushort8v*>(&xln[((size_t)which*NROWS + row)*DMODEL + lane*8]) = o;
  } else {
    int wb = b - 6144;
    const float* src = (wb>=64) ? Wo : Wi;
    unsigned short* dst = (wb>=64) ? WoT : WiT;
    int rc = wb & 63;
    int r0 = (rc>>3)*64, c0 = (rc&7)*64;
    for (int it=0; it<4; ++it){
      int idx = it*256+t, row = idx>>4, q = idx&15;
      float4 v = *reinterpret_cast<const float4*>(&src[(size_t)(r0+row)*DMODEL + c0 + q*4]);
      T[row][q*4+0]=v.x; T[row][q*4+1]=v.y; T[row][q*4+2]=v.z; T[row][q*4+3]=v.w;
    }
    __syncthreads();
    for (int it=0; it<4; ++it){
      int idx = it*256+t, oc = idx>>4, q = idx&15;
      ushort4v o;
      o[0]=f2bf(T[q*4+0][oc]); o[1]=f2bf(T[q*4+1][oc]);
      o[2]=f2bf(T[q*4+2][oc]); o[3]=f2bf(T[q*4+3][oc]);
      *reinterpret_cast<ushort4v*>(&dst[(size_t)(c0+oc)*DMODEL + r0 + q*4]) = o;
    }
  }
}

// ---------------------------------------------------------------- K1b: projection GEMM (pure bf16 MFMA) + row stats
__global__ void __launch_bounds__(256) proj_mfma_kernel(
    const unsigned short* __restrict__ xln,
    const unsigned short* __restrict__ WiT,
    unsigned short* __restrict__ fq, unsigned short* __restrict__ fk, unsigned short* __restrict__ fvT,
    float* __restrict__ aqA, float* __restrict__ i1qA,
    float* __restrict__ rskA, float* __restrict__ i1kA)
{
  int which = blockIdx.z;
  const unsigned short* src = xln + (size_t)which*NROWS*DMODEL;
  int r0 = blockIdx.x*128;   // x rows (n-dim)
  int c0 = blockIdx.y*128;   // output cols (head*64+d dim)
  __shared__ unsigned short XT[128*64];
  __shared__ unsigned short WT[128*64];
  int t = threadIdx.x;
  int w=t>>6, lane=t&63, l16=lane&15, lh=lane>>4;
  f32x4 acc[4][4];
  #pragma unroll
  for(int i=0;i<4;i++){ for(int j=0;j<4;j++) acc[i][j]=(f32x4){0.f,0.f,0.f,0.f}; }
  for (int k0=0;k0<DMODEL;k0+=64){
    __syncthreads();
    for (int it=0; it<4; ++it){
      int idx=it*256+t, row=idx>>3, q=idx&7;
      ushort8v v = *reinterpret_cast<const ushort8v*>(&src[(size_t)(r0+row)*DMODEL + k0 + q*8]);
      tile_st16(XT, row, 128, q*16, v);
    }
    for (int it=0; it<4; ++it){
      int idx=it*256+t, row=idx>>3, q=idx&7;
      ushort8v v = *reinterpret_cast<const ushort8v*>(&WiT[(size_t)(c0+row)*DMODEL + k0 + q*8]);
      tile_st16(WT, row, 128, q*16, v);
    }
    __syncthreads();
    if (which<2){
      int dr=(w&1)*64, nc=(w>>1)*64;
      #pragma unroll
      for (int ks=0; ks<2; ++ks){
        int kb = lh*16 + ks*64;
        short8 a[4], b[4];
        #pragma unroll
        for (int i=0;i<4;i++) a[i] = frag_ld(WT, dr+i*16+l16, 128, kb);
        #pragma unroll
        for (int j=0;j<4;j++) b[j] = frag_ld(XT, nc+j*16+l16, 128, kb);
        #pragma unroll
        for (int i=0;i<4;i++){
          #pragma unroll
          for (int j=0;j<4;j++) acc[i][j]=MFMA(a[i],b[j],acc[i][j]);
        }
      }
    } else {
      int nr=(w>>1)*64, dc=(w&1)*64;
      #pragma unroll
      for (int ks=0; ks<2; ++ks){
        int kb = lh*16 + ks*64;
        short8 a[4], b[4];
        #pragma unroll
        for (int i=0;i<4;i++) a[i] = frag_ld(XT, nr+i*16+l16, 128, kb);
        #pragma unroll
        for (int j=0;j<4;j++) b[j] = frag_ld(WT, dc+j*16+l16, 128, kb);
        #pragma unroll
        for (int i=0;i<4;i++){
          #pragma unroll
          for (int j=0;j<4;j++) acc[i][j]=MFMA(a[i],b[j],acc[i][j]);
        }
      }
    }
  }
  if (which<2){
    unsigned short* dst = which ? fk : fq;
    int dr=(w&1)*64, nc=(w>>1)*64;
    #pragma unroll
    for (int i=0;i<4;i++){
      #pragma unroll
      for (int j=0;j<4;j++){
        int cl = c0 + dr + i*16 + lh*4;
        int ng = r0 + nc + j*16 + l16;
        int head = cl>>6, dd = cl&63;
        int hq = head*QB + (ng>>9);
        int n = ng&511;
        ushort4v o;
        o[0]=f2bf(acc[i][j][0]); o[1]=f2bf(acc[i][j][1]);
        o[2]=f2bf(acc[i][j][2]); o[3]=f2bf(acc[i][j][3]);
        *reinterpret_cast<ushort4v*>(&dst[((size_t)hq*SEQ+n)*DHD + dd]) = o;
      }
    }
    // fused row stats: sum_d f, sum_d f^2 for this wave's head
    int head = (c0>>6) + (w&1);
    #pragma unroll
    for (int j=0;j<4;j++){
      float s=0.f, ss=0.f;
      #pragma unroll
      for (int i=0;i<4;i++){
        #pragma unroll
        for (int r=0;r<4;r++){ float x = acc[i][j][r]; s += x; ss = fmaf(x,x,ss); }
      }
      s += __shfl_xor(s,16,64); ss += __shfl_xor(ss,16,64);
      s += __shfl_xor(s,32,64); ss += __shfl_xor(ss,32,64);
      if (lh==0){
        int ng = r0 + nc + j*16 + l16;
        int hq = head*QB + (ng>>9);
        int n = ng&511;
        float nrm = sqrtf(ss);
        if (which==0){
          aqA[hq*SEQ+n]  = s*(1.0f/64.0f);
          i1qA[hq*SEQ+n] = 1.0f/(nrm+1e-8f);
        } else {
          rskA[hq*SEQ+n] = s;
          i1kA[hq*SEQ+n] = 1.0f/(nrm+1e-8f);
        }
      }
    }
  } else {
    int nr=(w>>1)*64, dc=(w&1)*64;
    #pragma unroll
    for (int i=0;i<4;i++){
      #pragma unroll
      for (int j=0;j<4;j++){
        int ngb = r0 + nr + i*16 + lh*4;
        int dg  = c0 + dc + j*16 + l16;
        int head = dg>>6, dd = dg&63;
        int hq = head*QB + (ngb>>9);
        int n = ngb&511;
        ushort4v o;
        o[0]=f2bf(acc[i][j][0]); o[1]=f2bf(acc[i][j][1]);
        o[2]=f2bf(acc[i][j][2]); o[3]=f2bf(acc[i][j][3]);
        *reinterpret_cast<ushort4v*>(&fvT[((size_t)hq*DHD+dd)*SEQ + n]) = o;
      }
    }
  }
}

// ---------------------------------------------------------------- S: full column stats (one block per hq,isk)
__global__ void __launch_bounds__(256) colstat_kernel(
    const unsigned short* __restrict__ fq, const unsigned short* __restrict__ fk,
    float* __restrict__ qgp, float* __restrict__ kgp, float* __restrict__ c2A)
{
  int hq = blockIdx.x, isk = blockIdx.y;
  const unsigned short* F = (isk ? fk : fq) + (size_t)hq*SEQ*DHD;
  int t = threadIdx.x, g = t&15, rg = t>>4;
  float acc0=0.f, acc1=0.f, acc2=0.f, acc3=0.f;
  #pragma unroll 4
  for (int i=0;i<32;i++){
    int r = rg + 16*i;
    ushort4v v = *reinterpret_cast<const ushort4v*>(&F[(size_t)r*DHD + g*4]);
    acc0+=bf2f(v[0]); acc1+=bf2f(v[1]); acc2+=bf2f(v[2]); acc3+=bf2f(v[3]);
  }
  __shared__ float sh[16][68];
  sh[rg][g*4+0]=acc0; sh[rg][g*4+1]=acc1; sh[rg][g*4+2]=acc2; sh[rg][g*4+3]=acc3;
  __syncthreads();
  if (t<64){
    float s=0.f;
    #pragma unroll
    for (int r=0;r<16;r++) s += sh[r][t];
    if (isk){
      kgp[hq*64+t]=s;
      float c = s*(1.0f/512.0f);
      #pragma unroll
      for (int m=32;m>0;m>>=1) c += __shfl_xor(c,m,64);
      if (t==0) c2A[hq]=c;
    } else {
      qgp[hq*64+t]=s;
    }
  }
}

// ---------------------------------------------------------------- M1: moments + rowmax + c1 (LDS-staged, XCD-local grid)
__global__ void __launch_bounds__(256) score_m1_kernel(
    const unsigned short* __restrict__ fq, const unsigned short* __restrict__ fk,
    const float* __restrict__ aqA, const float* __restrict__ i1qA,
    const float* __restrict__ rskA, const float* __restrict__ i1kA,
    const float* __restrict__ c2A, const float* __restrict__ kgp,
    float* __restrict__ c1A, float* __restrict__ rmaxcA, float* __restrict__ rmaxoA,
    float* __restrict__ momf, double* __restrict__ varp)
{
  // grid (QB, NH, 8): strip slowest -> same-(h,q) blocks land on one XCD
  int q_=blockIdx.x, h=blockIdx.y, strip=blockIdx.z;
  int hq=h*QB+q_, n0=strip*64;
  const unsigned short* Fq=fq+(size_t)hq*SEQ*DHD;
  const unsigned short* Fk=fk+(size_t)hq*SEQ*DHD;
  __shared__ unsigned short KT[128*64];
  __shared__ float rskL[512], i1kL[512];
  __shared__ float red[256];
  __shared__ double dred[256];
  int t=threadIdx.x, w=t>>6, lane=t&63, l16=lane&15, lh=lane>>4;
  int n = n0 + w*16 + l16;
  for (int i=t;i<512;i+=256){ rskL[i]=rskA[hq*SEQ+i]; i1kL[i]=i1kA[hq*SEQ+i]; }
  float c2v = c2A[hq];
  float aqv = aqA[hq*SEQ+n];
  float iq1 = i1qA[hq*SEQ+n];
  short8 qa[2];
  #pragma unroll
  for (int ks=0;ks<2;ks++)
    qa[ks] = *reinterpret_cast<const short8*>(&Fq[(size_t)n*DHD + ks*32 + lh*8]);
  // c1[n] = fq[n] . (kgp/512)
  float c1v = 0.f;
  #pragma unroll
  for (int ks=0;ks<2;ks++){
    const float* bkp = &kgp[hq*64 + ks*32 + lh*8];
    float4 b0 = *reinterpret_cast<const float4*>(bkp);
    float4 b1 = *reinterpret_cast<const float4*>(bkp+4);
    float bb[8] = {b0.x,b0.y,b0.z,b0.w,b1.x,b1.y,b1.z,b1.w};
    #pragma unroll
    for (int i=0;i<8;i++) c1v = fmaf(bf2f((unsigned short)qa[ks][i]), bb[i], c1v);
  }
  c1v *= (1.0f/512.0f);
  c1v += __shfl_xor(c1v,16,64);
  c1v += __shfl_xor(c1v,32,64);
  if (lane<16) c1A[hq*SEQ+n] = c1v;
  float c1x = KCOV*(c1v - aqv*c2v);
  float aqx = KCOV*aqv;
  float sc=0.f,sc2=0.f,so=0.f,so2=0.f,sco=0.f;
  float rc=0.f, ro=0.f, rm=0.f, rmc=-1e30f, rmo=-1e30f;
  for (int mc=0;mc<4;mc++){
    int m0=mc*128;
    __syncthreads();
    for (int it=0;it<4;++it){
      int idx=it*256+t, row=idx>>3, qc=idx&7;
      ushort8v vv = *reinterpret_cast<const ushort8v*>(&Fk[(size_t)(m0+row)*DHD + qc*8]);
      tile_st16(KT,row,128,qc*16,vv);
    }
    __syncthreads();
    #pragma unroll
    for (int mh=0;mh<2;mh++){
      int mb = mh*64;
      f32x4 acc[4];
      #pragma unroll
      for (int mf=0;mf<4;mf++) acc[mf]=(f32x4){0.f,0.f,0.f,0.f};
      #pragma unroll
      for (int mf=0;mf<4;mf++){
        #pragma unroll
        for (int ks=0;ks<2;ks++){
          short8 kf = frag_ld(KT, mb+mf*16+l16, 128, lh*16+ks*64);
          acc[mf] = MFMA(kf, qa[ks], acc[mf]);
        }
      }
      #pragma unroll
      for (int mf=0;mf<4;mf++){
        int ml = m0 + mb + mf*16 + lh*4;
        float4 rsk4 = *reinterpret_cast<const float4*>(&rskL[ml]);
        float4 i1k4 = *reinterpret_cast<const float4*>(&i1kL[ml]);
        float rk[4]={rsk4.x,rsk4.y,rsk4.z,rsk4.w};
        float ik[4]={i1k4.x,i1k4.y,i1k4.z,i1k4.w};
        #pragma unroll
        for (int r=0;r<4;r++){
          float S = acc[mf][r];
          float cosv = clampf(S*iq1*ik[r], -0.99f, 0.99f);
          float u = fmaf(KCOV, S, -c1x);
          float covv = fmaf(-aqx, rk[r], u);
          covv = clampf(covv, -10.0f, 10.0f);
          float marg = clampf(0.01f - cosv, 0.0f, 2.0f);
          sc += cosv; sc2 = fmaf(cosv,cosv,sc2);
          so += covv; so2 = fmaf(covv,covv,so2);
          sco = fmaf(cosv,covv,sco);
          rc += cosv; ro += covv; rm += marg;
          rmc = fmaxf(rmc, cosv); rmo = fmaxf(rmo, covv);
        }
      }
    }
  }
  // row reductions across lh (lanes sharing l16)
  rc += __shfl_xor(rc,16,64); rc += __shfl_xor(rc,32,64);
  ro += __shfl_xor(ro,16,64); ro += __shfl_xor(ro,32,64);
  rm += __shfl_xor(rm,16,64); rm += __shfl_xor(rm,32,64);
  rmc = fmaxf(rmc, __shfl_xor(rmc,16,64)); rmc = fmaxf(rmc, __shfl_xor(rmc,32,64));
  rmo = fmaxf(rmo, __shfl_xor(rmo,16,64)); rmo = fmaxf(rmo, __shfl_xor(rmo,32,64));
  if (lane<16){
    rmaxcA[hq*SEQ+n] = rmc;
    rmaxoA[hq*SEQ+n] = rmo;
  }
  double vm=0.0, vm2=0.0, vmc=0.0, vmo=0.0;
  if (lane<16){
    float mm = rm*(1.0f/512.0f);
    vm  = (double)mm;
    vm2 = (double)mm*(double)mm;
    vmc = (double)mm*(double)rc;
    vmo = (double)mm*(double)ro;
  }
  float fs[5]={sc,sc2,so,so2,sco};
  for (int c=0;c<5;c++){
    __syncthreads();
    red[t]=fs[c]; __syncthreads();
    for (int o=128;o>0;o>>=1){ if (t<o) red[t]+=red[t+o]; __syncthreads(); }
    if (t==0) momf[(size_t)(hq*8+strip)*5 + c] = red[0];
  }
  double ds[4]={vm,vm2,vmc,vmo};
  for (int c=0;c<4;c++){
    __syncthreads();
    dred[t]=ds[c]; __syncthreads();
    for (int o=128;o>0;o>>=1){ if (t<o) dred[t]+=dred[t+o]; __syncthreads(); }
    if (t==0) varp[(size_t)(hq*8+strip)*4 + c] = dred[0];
  }
}

// ---------------------------------------------------------------- F: MLP + stds + mix params
__global__ void __launch_bounds__(256) finalize_kernel(
    const float* __restrict__ qgp, const float* __restrict__ kgp,
    const float* __restrict__ wp1w, const float* __restrict__ wp1b,
    const float* __restrict__ wplg, const float* __restrict__ wplb,
    const float* __restrict__ wp2w, const float* __restrict__ wp2b,
    const float* __restrict__ wp3w, const float* __restrict__ wp3b,
    const float* __restrict__ temp,
    const float* __restrict__ momf, const double* __restrict__ varp,
    float* __restrict__ params)
{
  int t = threadIdx.x;
  __shared__ float feats[8][128];
  __shared__ float h1s[8][64];
  __shared__ float h2s[8][32];
  __shared__ float wts[8][3];
  __shared__ double Sh[8][9];
  for (int idx=t; idx<512; idx+=256){
    int h = idx>>6, d = idx&63;
    float s1=0, s2=0;
    for (int qq=0; qq<QB; qq++){ s1 += qgp[(h*QB+qq)*64+d]; s2 += kgp[(h*QB+qq)*64+d]; }
    feats[h][d]    = s1*(1.0f/8192.0f);
    feats[h][64+d] = s2*(1.0f/8192.0f);
  }
  __syncthreads();
  int w = t>>6, j = t&63;
  for (int pp=0; pp<2; pp++){
    int h = w + pp*4;
    float acc = wp1b[j];
    for (int k=0;k<128;k++) acc += feats[h][k]*wp1w[k*64+j];
    float s=acc, s2=acc*acc;
    #pragma unroll
    for (int m=32;m>0;m>>=1){ s+=__shfl_xor(s,m,64); s2+=__shfl_xor(s2,m,64); }
    float mean = s*(1.0f/64.0f);
    float var  = s2*(1.0f/64.0f) - mean*mean;
    float xh = (acc-mean)*rsqrtf(var+1e-5f)*wplg[j] + wplb[j];
    h1s[h][j] = fmaxf(xh, 0.0f);
  }
  __syncthreads();
  {
    int h = t>>5, j2 = t&31;
    float acc = wp2b[j2];
    for (int k=0;k<64;k++) acc += h1s[h][k]*wp2w[k*32+j2];
    h2s[h][j2] = fmaxf(acc, 0.0f);
  }
  __syncthreads();
  if (t<8){
    int h = t;
    float z[3] = {wp3b[0], wp3b[1], wp3b[2]};
    for (int k=0;k<32;k++){
      float hv = h2s[h][k];
      z[0]+=hv*wp3w[k*3]; z[1]+=hv*wp3w[k*3+1]; z[2]+=hv*wp3w[k*3+2];
    }
    float mx = fmaxf(z[0], fmaxf(z[1], z[2]));
    float e0=expf(z[0]-mx), e1=expf(z[1]-mx), e2=expf(z[2]-mx);
    float inv = 1.0f/(e0+e1+e2);
    float l0=e0*inv, l1=e1*inv, l2=e2*inv;
    float tv = temp[0]; tv = fminf(fmaxf(tv, 0.1f), 20.0f);
    float y0=l0/tv, y1=l1/tv, y2=l2/tv;
    float mx2 = fmaxf(y0, fmaxf(y1, y2));
    float f0=expf(y0-mx2), f1=expf(y1-mx2), f2=expf(y2-mx2);
    float inv2 = 1.0f/(f0+f1+f2);
    wts[h][0]=f0*inv2; wts[h][1]=f1*inv2; wts[h][2]=f2*inv2;
  }
  __syncthreads();
  if (t<40){
    int h = t/5, c = t%5;
    double s = 0;
    for (int e=0; e<128; e++) s += (double)momf[(size_t)(h*128+e)*5 + c];
    Sh[h][c] = s;
  }
  __syncthreads();
  if (t<32){
    int h = t>>2, c = t&3;
    double s = 0;
    for (int e=0; e<128; e++) s += varp[(size_t)(h*128+e)*4 + c];
    Sh[h][5+c] = s;
  }
  __syncthreads();
  if (t==0){
    const double Ntot = 33554432.0;
    double T1c=0,T2c=0,T1o=0,T2o=0,T1v=0,T2v=0;
    for (int h=0;h<8;h++){
      T1c+=Sh[h][0]; T2c+=Sh[h][1]; T1o+=Sh[h][2]; T2o+=Sh[h][3];
      T1v+=512.0*Sh[h][5]; T2v+=512.0*Sh[h][6];
    }
    double stdc = sqrt(fmax((T2c - T1c*T1c/Ntot)/(Ntot-1.0), 0.0));
    double stdo = sqrt(fmax((T2o - T1o*T1o/Ntot)/(Ntot-1.0), 0.0));
    double stdv = sqrt(fmax((T2v - T1v*T1v/Ntot)/(Ntot-1.0), 0.0));
    double ah[8], bh[8];
    double Sd1=0, Sd2=0;
    for (int h=0;h<8;h++){
      double a = (double)wts[h][0]/(stdc+1e-8);
      double b = (double)wts[h][1]*0.1/(stdo+1e-8);
      double c = (double)wts[h][2]*0.1/(stdv+1e-8);
      ah[h]=a; bh[h]=b;
      Sd1 += a*Sh[h][0] + b*Sh[h][2] + c*512.0*Sh[h][5];
      Sd2 += a*a*Sh[h][1] + b*b*Sh[h][3] + c*c*512.0*Sh[h][6]
           + 2.0*a*b*Sh[h][4] + 2.0*a*c*Sh[h][7] + 2.0*b*c*Sh[h][8];
    }
    double stdd = sqrt(fmax((Sd2 - Sd1*Sd1/Ntot)/(Ntot-1.0), 0.0));
    double att = 1.0 + 0.5*stdd;
    att = fmin(fmax(att, 0.5), 5.0);
    double scale = 1.0/att;
    for (int h=0;h<8;h++){
      params[h*2+0] = (float)(scale*ah[h]);
      params[h*2+1] = (float)(scale*bh[h]);
    }
  }
}

// ---------------------------------------------------------------- M2: fixed-max softmax + PV (LDS-staged, XCD-local grid)
__global__ void __launch_bounds__(256) attn_m2_kernel(
    const unsigned short* __restrict__ fq, const unsigned short* __restrict__ fk,
    const unsigned short* __restrict__ fvT,
    const float* __restrict__ aqA, const float* __restrict__ c1A, const float* __restrict__ i1qA,
    const float* __restrict__ rskA, const float* __restrict__ i1kA,
    const float* __restrict__ c2A, const float* __restrict__ params,
    const float* __restrict__ rmaxcA, const float* __restrict__ rmaxoA,
    unsigned short* __restrict__ attn_bf)
{
  // grid (QB, NH, 8): strip slowest -> same-(h,q) blocks land on one XCD
  int q_=blockIdx.x, h=blockIdx.y, strip=blockIdx.z;
  int hq=h*QB+q_, n0=strip*64;
  const unsigned short* Fq=fq+(size_t)hq*SEQ*DHD;
  const unsigned short* Fk=fk+(size_t)hq*SEQ*DHD;
  const unsigned short* FvT=fvT+(size_t)hq*DHD*SEQ;
  __shared__ unsigned short KT[128*64];     // K rows (m) x 64 d
  __shared__ unsigned short VT[64*128];     // [d][m], pitch 256B
  __shared__ unsigned short P[64*64];       // [n][m-half] bf16, pitch 128B
  __shared__ float rskL[512], i1kL[512];
  int t=threadIdx.x, w=t>>6, lane=t&63, l16=lane&15, lh=lane>>4;
  int n = n0 + w*16 + l16;
  for (int i=t;i<512;i+=256){ rskL[i]=rskA[hq*SEQ+i]; i1kL[i]=i1kA[hq*SEQ+i]; }
  float c2v=c2A[hq];
  float pa=params[h*2], pb=params[h*2+1];
  float aqv = aqA[hq*SEQ+n];
  float c1v = c1A[hq*SEQ+n];
  float iq1 = i1qA[hq*SEQ+n];
  float rmc = rmaxcA[hq*SEQ+n];
  float rmo = rmaxoA[hq*SEQ+n];
  float pbk = pb*KCOV;
  float ra  = pa*iq1;
  float bndc = 0.99f*pa;
  float rowc = -pbk*(c1v - aqv*c2v);
  float r3   = pbk*aqv;
  float Mrow = fmaf(pa, rmc, pb*rmo);
  short8 qa[2];
  #pragma unroll
  for (int ks=0;ks<2;ks++)
    qa[ks] = *reinterpret_cast<const short8*>(&Fq[(size_t)n*DHD + ks*32 + lh*8]);
  short8 ones;
  #pragma unroll
  for (int i=0;i<8;i++) ones[i] = (short)0x3F80;
  f32x4 accO[4];
  #pragma unroll
  for (int j=0;j<4;j++) accO[j]=(f32x4){0.f,0.f,0.f,0.f};
  f32x4 den = (f32x4){0.f,0.f,0.f,0.f};
  int prow = w*16 + l16;
  for (int mc=0;mc<4;mc++){
    int m0=mc*128;
    __syncthreads();
    for (int it=0;it<4;++it){
      int idx=it*256+t, row=idx>>3, qc=idx&7;
      ushort8v vv = *reinterpret_cast<const ushort8v*>(&Fk[(size_t)(m0+row)*DHD + qc*8]);
      tile_st16(KT,row,128,qc*16,vv);
    }
    for (int it=0;it<4;++it){
      int idx=it*256+t, dd=idx>>4, c=idx&15;
      ushort8v vv=*reinterpret_cast<const ushort8v*>(&FvT[(size_t)dd*SEQ + m0 + c*8]);
      tile_st16(VT, dd, 256, c*16, vv);
    }
    __syncthreads();
    #pragma unroll
    for (int mh=0;mh<2;mh++){
      int mb = mh*64;
      // QK^T (swapped): acc rows = K rows m, cols = own n
      f32x4 acc[4];
      #pragma unroll
      for (int mf=0;mf<4;mf++) acc[mf]=(f32x4){0.f,0.f,0.f,0.f};
      #pragma unroll
      for (int mf=0;mf<4;mf++){
        #pragma unroll
        for (int ks=0;ks<2;ks++){
          short8 kf = frag_ld(KT, mb+mf*16+l16, 128, lh*16+ks*64);
          acc[mf] = MFMA(kf, qa[ks], acc[mf]);
        }
      }
      // transform + exp(logit - Mrow), write P[n][m] packed
      #pragma unroll
      for (int mf=0;mf<4;mf++){
        int ml = m0 + mb + mf*16 + lh*4;
        float4 rsk4 = *reinterpret_cast<const float4*>(&rskL[ml]);
        float4 i1k4 = *reinterpret_cast<const float4*>(&i1kL[ml]);
        float rk[4]={rsk4.x,rsk4.y,rsk4.z,rsk4.w};
        float ik[4]={i1k4.x,i1k4.y,i1k4.z,i1k4.w};
        #pragma unroll
        for (int r=0;r<4;r++){
          float S = acc[mf][r];
          float tt = S*ra; tt *= ik[r];
          float cc = clampf(tt, -bndc, bndc);
          float u = fmaf(pbk, S, rowc);
          float lin = fmaf(-r3, rk[r], u);
          acc[mf][r] = __expf(cc + lin - Mrow);
        }
        unsigned lo = cvtpk(acc[mf][0], acc[mf][1]);
        unsigned hi = cvtpk(acc[mf][2], acc[mf][3]);
        int pbyte = (mf*32 + lh*8) ^ ((prow&7)<<4);
        *reinterpret_cast<uint2*>(reinterpret_cast<char*>(P) + prow*128 + pbyte)
          = make_uint2(lo, hi);
      }
      // PV + denominator (wave-local P rows; in-wave LDS ordering suffices)
      #pragma unroll
      for (int ks=0;ks<2;ks++){
        short8 pfrag = frag_ld(P, prow, 128, lh*16 + ks*64);
        #pragma unroll
        for (int dcf=0;dcf<4;dcf++){
          short8 vb = frag_ld(VT, dcf*16+l16, 256, mb*2 + ks*64 + lh*16);
          accO[dcf] = MFMA(pfrag, vb, accO[dcf]);
        }
        den = MFMA(pfrag, ones, den);
      }
    }
  }
  // epilogue: normalize, bounce through P, coalesced store
  f32x4 invD;
  #pragma unroll
  for (int r=0;r<4;r++) invD[r] = 1.0f/den[r];
  __syncthreads();
  #pragma unroll
  for (int dcf=0;dcf<4;dcf++){
    #pragma unroll
    for (int r=0;r<4;r++){
      int row = w*16 + lh*4 + r;
      int col = dcf*16 + l16;
      int addr = row*128 + ((col*2) ^ ((row&7)<<4));
      *reinterpret_cast<unsigned short*>(reinterpret_cast<char*>(P) + addr)
        = f2bf(accO[dcf][r]*invD[r]);
    }
  }
  __syncthreads();
  for (int it=0; it<2; ++it){
    int idx = it*256 + t;
    int row = idx>>3, c = idx&7;
    int addr = row*128 + ((c*16) ^ ((row&7)<<4));
    ushort8v vv = *reinterpret_cast<ushort8v*>(reinterpret_cast<char*>(P) + addr);
    *reinterpret_cast<ushort8v*>(
      &attn_bf[(size_t)(q_*SEQ + n0 + row)*DMODEL + h*DHD + c*8]) = vv;
  }
}

// ---------------------------------------------------------------- KO: output projection (MFMA)
__global__ void __launch_bounds__(256) out_mfma_kernel(
    const unsigned short* __restrict__ attn_bf, const unsigned short* __restrict__ WoT,
    const float* __restrict__ bias, float* __restrict__ out)
{
  int r0=blockIdx.x*128;
  int c0=blockIdx.y*128;
  __shared__ unsigned short AT[128*64];
  __shared__ unsigned short WT[128*64];
  int t=threadIdx.x, w=t>>6, lane=t&63, l16=lane&15, lh=lane>>4;
  f32x4 acc[4][4];
  #pragma unroll
  for(int i=0;i<4;i++){ for(int j=0;j<4;j++) acc[i][j]=(f32x4){0.f,0.f,0.f,0.f}; }
  for (int k0=0;k0<DMODEL;k0+=64){
    __syncthreads();
    for (int it=0; it<4; ++it){
      int idx=it*256+t, row=idx>>3, q=idx&7;
      ushort8v v = *reinterpret_cast<const ushort8v*>(&attn_bf[(size_t)(r0+row)*DMODEL + k0 + q*8]);
      tile_st16(AT, row, 128, q*16, v);
    }
    for (int it=0; it<4; ++it){
      int idx=it*256+t, row=idx>>3, q=idx&7;
      ushort8v v = *reinterpret_cast<const ushort8v*>(&WoT[(size_t)(c0+row)*DMODEL + k0 + q*8]);
      tile_st16(WT, row, 128, q*16, v);
    }
    __syncthreads();
    int nr=(w&1)*64, mr=(w>>1)*64;
    #pragma unroll
    for (int ks=0; ks<2; ++ks){
      int kb = lh*16 + ks*64;
      short8 a[4], b[4];
      #pragma unroll
      for (int i=0;i<4;i++) a[i] = frag_ld(WT, nr+i*16+l16, 128, kb);
      #pragma unroll
      for (int j=0;j<4;j++) b[j] = frag_ld(AT, mr+j*16+l16, 128, kb);
      #pragma unroll
      for (int i=0;i<4;i++){
        #pragma unroll
        for (int j=0;j<4;j++) acc[i][j]=MFMA(a[i],b[j],acc[i][j]);
      }
    }
  }
  #pragma unroll
  for (int i=0;i<4;i++){
    int nb = c0+(w&1)*64+i*16+lh*4;
    float4 b4 = *reinterpret_cast<const float4*>(&bias[nb]);
    #pragma unroll
    for (int j=0;j<4;j++){
      int mg = r0+(w>>1)*64+j*16+l16;
      f32x4 o = acc[i][j];
      o[0]+=b4.x; o[1]+=b4.y; o[2]+=b4.z; o[3]+=b4.w;
      *reinterpret_cast<f32x4*>(&out[(size_t)mg*DMODEL + nb]) = o;
    }
  }
}

// ----------------------------------------------------------------
extern "C" void kernel_launch(void* const* d_in, const int* in_sizes, int n_in,
                              void* d_out, int out_size, void* d_ws, size_t ws_size,
                              hipStream_t stream)
{
  (void)in_sizes; (void)n_in; (void)out_size; (void)ws_size;
  const float* q     = (const float*)d_in[0];
  const float* k     = (const float*)d_in[1];
  const float* v     = (const float*)d_in[2];
  const float* ln_g  = (const float*)d_in[3];
  const float* ln_b  = (const float*)d_in[4];
  const float* W_in  = (const float*)d_in[5];
  const float* wp1w  = (const float*)d_in[6];
  const float* wp1b  = (const float*)d_in[7];
  const float* wplg  = (const float*)d_in[8];
  const float* wplb  = (const float*)d_in[9];
  const float* wp2w  = (const float*)d_in[10];
  const float* wp2b  = (const float*)d_in[11];
  const float* wp3w  = (const float*)d_in[12];
  const float* wp3b  = (const float*)d_in[13];
  const float* temp  = (const float*)d_in[14];
  const float* W_out = (const float*)d_in[15];
  const float* b_out = (const float*)d_in[16];
  float* out = (float*)d_out;

  char* wsb = (char*)d_ws;
  size_t off = 0;
  auto alloc = [&](size_t bytes)->char*{
    char* p = wsb + off; off += (bytes + 255) & ~(size_t)255; return p;
  };
  unsigned short* xln    = (unsigned short*)alloc((size_t)3*NROWS*DMODEL*2);
  unsigned short* fq_b   = (unsigned short*)alloc((size_t)NHQ*SEQ*DHD*2);
  unsigned short* fk_b   = (unsigned short*)alloc((size_t)NHQ*SEQ*DHD*2);
  unsigned short* fvT_b  = (unsigned short*)alloc((size_t)NHQ*SEQ*DHD*2);
  unsigned short* attn_b = (unsigned short*)alloc((size_t)NROWS*DMODEL*2);
  unsigned short* WiT    = (unsigned short*)alloc((size_t)DMODEL*DMODEL*2);
  unsigned short* WoT    = (unsigned short*)alloc((size_t)DMODEL*DMODEL*2);
  float* aqA    = (float*)alloc(NHQ*SEQ*4);
  float* c1A    = (float*)alloc(NHQ*SEQ*4);
  float* i1qA   = (float*)alloc(NHQ*SEQ*4);
  float* rskA   = (float*)alloc(NHQ*SEQ*4);
  float* i1kA   = (float*)alloc(NHQ*SEQ*4);
  float* rmaxcA = (float*)alloc(NHQ*SEQ*4);
  float* rmaxoA = (float*)alloc(NHQ*SEQ*4);
  float* c2A    = (float*)alloc(NHQ*4);
  float* qgp    = (float*)alloc(NHQ*64*4);
  float* kgp    = (float*)alloc(NHQ*64*4);
  float* momf   = (float*)alloc((size_t)NHQ*8*5*4);
  double* varp  = (double*)alloc((size_t)NHQ*8*4*8);
  float* params = (float*)alloc(64);

  prep_kernel<<<6272, 256, 0, stream>>>(q, k, v, ln_g, ln_b, W_in, W_out, xln, WiT, WoT);
  proj_mfma_kernel<<<dim3(64,4,3), 256, 0, stream>>>(xln, WiT, fq_b, fk_b, fvT_b,
                                                     aqA, i1qA, rskA, i1kA);
  colstat_kernel<<<dim3(NHQ, 2), 256, 0, stream>>>(fq_b, fk_b, qgp, kgp, c2A);
  score_m1_kernel<<<dim3(QB, NH, 8), 256, 0, stream>>>(fq_b, fk_b, aqA, i1qA, rskA, i1kA,
                                                       c2A, kgp, c1A, rmaxcA, rmaxoA, momf, varp);
  finalize_kernel<<<1, 256, 0, stream>>>(qgp, kgp, wp1w, wp1b, wplg, wplb, wp2w, wp2b,
                                         wp3w, wp3b, temp, momf, varp, params);
  attn_m2_kernel<<<dim3(QB, NH, 8), 256, 0, stream>>>(fq_b, fk_b, fvT_b, aqA, c1A, i1qA,
                                                      rskA, i1kA, c2A, params, rmaxcA, rmaxoA, attn_b);
  out_mfma_kernel<<<dim3(64,4), 256, 0, stream>>>(attn_b, WoT, b_out, out);
}

// Round 8
// 138.689 us; speedup vs baseline: 1.3981x; 1.1767x over previous
//
#include <hip/hip_runtime.h>
#include <math.h>

#define NH 8
#define DHD 64
#define DMODEL 512
#define QB 16
#define SEQ 512
#define NROWS (QB*SEQ)      /* 8192 rows per input */
#define NHQ (NH*QB)         /* 128 (h,q) pairs */
#define KCOV ((float)((0.001/512.0)/(8.0+1e-8)))

typedef __attribute__((ext_vector_type(8))) short short8;      // 8 bf16 -> 4 VGPR
typedef __attribute__((ext_vector_type(8))) unsigned short ushort8v;
typedef __attribute__((ext_vector_type(4))) unsigned short ushort4v;
typedef __attribute__((ext_vector_type(4))) float f32x4;

__device__ __forceinline__ float bf2f(unsigned short u){
  union { unsigned int i; float f; } c; c.i = ((unsigned int)u)<<16; return c.f;
}
__device__ __forceinline__ unsigned short f2bf(float f){
  union { float f; unsigned int i; } c; c.f = f;
  unsigned int u = c.i;
  u += 0x7fffu + ((u>>16)&1u);   // RNE
  return (unsigned short)(u>>16);
}
__device__ __forceinline__ unsigned cvtpk(float a, float b){
  unsigned r; asm("v_cvt_pk_bf16_f32 %0, %1, %2" : "=v"(r) : "v"(a), "v"(b)); return r;
}
__device__ __forceinline__ float clampf(float x, float lo, float hi){ return fminf(fmaxf(x,lo),hi); }

__device__ __forceinline__ f32x4 MFMA(short8 a, short8 b, f32x4 c){
  return __builtin_amdgcn_mfma_f32_16x16x32_bf16(a, b, c, 0, 0, 0);
}
// swizzled-tile access: element (row, kbyte), rowbytes pitch, XOR-swizzle bits 4-6 by row&7
__device__ __forceinline__ short8 frag_ld(const unsigned short* T, int row, int rowbytes, int kbyte){
  int addr = row*rowbytes + (kbyte ^ ((row&7)<<4));
  return *reinterpret_cast<const short8*>(reinterpret_cast<const char*>(T) + addr);
}
__device__ __forceinline__ void tile_st16(unsigned short* T, int row, int rowbytes, int kbyte, ushort8v v){
  int addr = row*rowbytes + (kbyte ^ ((row&7)<<4));
  *reinterpret_cast<ushort8v*>(reinterpret_cast<char*>(T) + addr) = v;
}

// ---------------------------------------------------------------- P0: LN stats+apply (bf16 out) + weight convert
__global__ void __launch_bounds__(256) prep_kernel(
    const float* __restrict__ xq, const float* __restrict__ xk, const float* __restrict__ xv,
    const float* __restrict__ ln_g, const float* __restrict__ ln_b,
    const float* __restrict__ Wi, const float* __restrict__ Wo,
    unsigned short* __restrict__ xln,
    unsigned short* __restrict__ WiT, unsigned short* __restrict__ WoT)
{
  __shared__ float T[64][68];
  int b = blockIdx.x, t = threadIdx.x;
  if (b < 6144){
    int which = b >> 11, rowblk = b & 2047;
    const float* src = which==0 ? xq : (which==1 ? xk : xv);
    int w = t >> 6, lane = t & 63;
    int row = rowblk*4 + w;
    const float* x = src + (size_t)row*DMODEL;
    float4 v1 = *reinterpret_cast<const float4*>(&x[lane*8]);
    float4 v2 = *reinterpret_cast<const float4*>(&x[lane*8+4]);
    float s  = v1.x+v1.y+v1.z+v1.w + v2.x+v2.y+v2.z+v2.w;
    float ss = v1.x*v1.x+v1.y*v1.y+v1.z*v1.z+v1.w*v1.w
             + v2.x*v2.x+v2.y*v2.y+v2.z*v2.z+v2.w*v2.w;
    #pragma unroll
    for (int m=32; m>0; m>>=1){ s += __shfl_xor(s,m,64); ss += __shfl_xor(ss,m,64); }
    float m_ = s*(1.0f/DMODEL);
    float var = ss*(1.0f/DMODEL) - m_*m_;
    float r_ = rsqrtf(var + 1e-5f);
    float4 g1 = *reinterpret_cast<const float4*>(&ln_g[lane*8]);
    float4 g2 = *reinterpret_cast<const float4*>(&ln_g[lane*8+4]);
    float4 b1 = *reinterpret_cast<const float4*>(&ln_b[lane*8]);
    float4 b2 = *reinterpret_cast<const float4*>(&ln_b[lane*8+4]);
    ushort8v o;
    o[0]=f2bf((v1.x-m_)*r_*g1.x + b1.x);
    o[1]=f2bf((v1.y-m_)*r_*g1.y + b1.y);
    o[2]=f2bf((v1.z-m_)*r_*g1.z + b1.z);
    o[3]=f2bf((v1.w-m_)*r_*g1.w + b1.w);
    o[4]=f2bf((v2.x-m_)*r_*g2.x + b2.x);
    o[5]=f2bf((v2.y-m_)*r_*g2.y + b2.y);
    o[6]=f2bf((v2.z-m_)*r_*g2.z + b2.z);
    o[7]=f2bf((v2.w-m_)*r_*g2.w + b2.w);
    *reinterpret_cast<ushort8v*>(&xln[((size_t)which*NROWS + row)*DMODEL + lane*8]) = o;
  } else {
    int wb = b - 6144;
    const float* src = (wb>=64) ? Wo : Wi;
    unsigned short* dst = (wb>=64) ? WoT : WiT;
    int rc = wb & 63;
    int r0 = (rc>>3)*64, c0 = (rc&7)*64;
    for (int it=0; it<4; ++it){
      int idx = it*256+t, row = idx>>4, q = idx&15;
      float4 v = *reinterpret_cast<const float4*>(&src[(size_t)(r0+row)*DMODEL + c0 + q*4]);
      T[row][q*4+0]=v.x; T[row][q*4+1]=v.y; T[row][q*4+2]=v.z; T[row][q*4+3]=v.w;
    }
    __syncthreads();
    for (int it=0; it<4; ++it){
      int idx = it*256+t, oc = idx>>4, q = idx&15;
      ushort4v o;
      o[0]=f2bf(T[q*4+0][oc]); o[1]=f2bf(T[q*4+1][oc]);
      o[2]=f2bf(T[q*4+2][oc]); o[3]=f2bf(T[q*4+3][oc]);
      *reinterpret_cast<ushort4v*>(&dst[(size_t)(c0+oc)*DMODEL + r0 + q*4]) = o;
    }
  }
}

// ---------------------------------------------------------------- K1b: projection GEMM (reg-pipelined staging)
__global__ void __launch_bounds__(256) proj_mfma_kernel(
    const unsigned short* __restrict__ xln,
    const unsigned short* __restrict__ WiT,
    unsigned short* __restrict__ fq, unsigned short* __restrict__ fk, unsigned short* __restrict__ fvT,
    float* __restrict__ aqA, float* __restrict__ i1qA,
    float* __restrict__ rskA, float* __restrict__ i1kA)
{
  int which = blockIdx.z;
  const unsigned short* src = xln + (size_t)which*NROWS*DMODEL;
  int r0 = blockIdx.x*128;   // x rows (n-dim)
  int c0 = blockIdx.y*128;   // output cols (head*64+d dim)
  __shared__ unsigned short XT[128*64];
  __shared__ unsigned short WT[128*64];
  int t = threadIdx.x;
  int w=t>>6, lane=t&63, l16=lane&15, lh=lane>>4;
  int srow = t>>3, sq = t&7;     // staging row/col for this thread (rows srow, srow+32, srow+64, srow+96)
  f32x4 acc[4][4];
  #pragma unroll
  for(int i=0;i<4;i++){ for(int j=0;j<4;j++) acc[i][j]=(f32x4){0.f,0.f,0.f,0.f}; }
  ushort8v xr[4], wr[4];
  #pragma unroll
  for (int it=0; it<4; ++it){
    xr[it] = *reinterpret_cast<const ushort8v*>(&src[(size_t)(r0+srow+it*32)*DMODEL + sq*8]);
    wr[it] = *reinterpret_cast<const ushort8v*>(&WiT[(size_t)(c0+srow+it*32)*DMODEL + sq*8]);
  }
  for (int k0=0;k0<DMODEL;k0+=64){
    __syncthreads();
    #pragma unroll
    for (int it=0; it<4; ++it){
      tile_st16(XT, srow+it*32, 128, sq*16, xr[it]);
      tile_st16(WT, srow+it*32, 128, sq*16, wr[it]);
    }
    __syncthreads();
    if (k0+64 < DMODEL){
      #pragma unroll
      for (int it=0; it<4; ++it){
        xr[it] = *reinterpret_cast<const ushort8v*>(&src[(size_t)(r0+srow+it*32)*DMODEL + k0+64 + sq*8]);
        wr[it] = *reinterpret_cast<const ushort8v*>(&WiT[(size_t)(c0+srow+it*32)*DMODEL + k0+64 + sq*8]);
      }
    }
    if (which<2){
      int dr=(w&1)*64, nc=(w>>1)*64;
      #pragma unroll
      for (int ks=0; ks<2; ++ks){
        int kb = lh*16 + ks*64;
        short8 a[4], b[4];
        #pragma unroll
        for (int i=0;i<4;i++) a[i] = frag_ld(WT, dr+i*16+l16, 128, kb);
        #pragma unroll
        for (int j=0;j<4;j++) b[j] = frag_ld(XT, nc+j*16+l16, 128, kb);
        #pragma unroll
        for (int i=0;i<4;i++){
          #pragma unroll
          for (int j=0;j<4;j++) acc[i][j]=MFMA(a[i],b[j],acc[i][j]);
        }
      }
    } else {
      int nr=(w>>1)*64, dc=(w&1)*64;
      #pragma unroll
      for (int ks=0; ks<2; ++ks){
        int kb = lh*16 + ks*64;
        short8 a[4], b[4];
        #pragma unroll
        for (int i=0;i<4;i++) a[i] = frag_ld(XT, nr+i*16+l16, 128, kb);
        #pragma unroll
        for (int j=0;j<4;j++) b[j] = frag_ld(WT, dc+j*16+l16, 128, kb);
        #pragma unroll
        for (int i=0;i<4;i++){
          #pragma unroll
          for (int j=0;j<4;j++) acc[i][j]=MFMA(a[i],b[j],acc[i][j]);
        }
      }
    }
  }
  if (which<2){
    unsigned short* dst = which ? fk : fq;
    int dr=(w&1)*64, nc=(w>>1)*64;
    #pragma unroll
    for (int i=0;i<4;i++){
      #pragma unroll
      for (int j=0;j<4;j++){
        int cl = c0 + dr + i*16 + lh*4;
        int ng = r0 + nc + j*16 + l16;
        int head = cl>>6, dd = cl&63;
        int hq = head*QB + (ng>>9);
        int n = ng&511;
        ushort4v o;
        o[0]=f2bf(acc[i][j][0]); o[1]=f2bf(acc[i][j][1]);
        o[2]=f2bf(acc[i][j][2]); o[3]=f2bf(acc[i][j][3]);
        *reinterpret_cast<ushort4v*>(&dst[((size_t)hq*SEQ+n)*DHD + dd]) = o;
      }
    }
    // fused row stats: sum_d f, sum_d f^2 for this wave's head
    int head = (c0>>6) + (w&1);
    #pragma unroll
    for (int j=0;j<4;j++){
      float s=0.f, ss=0.f;
      #pragma unroll
      for (int i=0;i<4;i++){
        #pragma unroll
        for (int r=0;r<4;r++){ float x = acc[i][j][r]; s += x; ss = fmaf(x,x,ss); }
      }
      s += __shfl_xor(s,16,64); ss += __shfl_xor(ss,16,64);
      s += __shfl_xor(s,32,64); ss += __shfl_xor(ss,32,64);
      if (lh==0){
        int ng = r0 + nc + j*16 + l16;
        int hq = head*QB + (ng>>9);
        int n = ng&511;
        float nrm = sqrtf(ss);
        if (which==0){
          aqA[hq*SEQ+n]  = s*(1.0f/64.0f);
          i1qA[hq*SEQ+n] = 1.0f/(nrm+1e-8f);
        } else {
          rskA[hq*SEQ+n] = s;
          i1kA[hq*SEQ+n] = 1.0f/(nrm+1e-8f);
        }
      }
    }
  } else {
    int nr=(w>>1)*64, dc=(w&1)*64;
    #pragma unroll
    for (int i=0;i<4;i++){
      #pragma unroll
      for (int j=0;j<4;j++){
        int ngb = r0 + nr + i*16 + lh*4;
        int dg  = c0 + dc + j*16 + l16;
        int head = dg>>6, dd = dg&63;
        int hq = head*QB + (ngb>>9);
        int n = ngb&511;
        ushort4v o;
        o[0]=f2bf(acc[i][j][0]); o[1]=f2bf(acc[i][j][1]);
        o[2]=f2bf(acc[i][j][2]); o[3]=f2bf(acc[i][j][3]);
        *reinterpret_cast<ushort4v*>(&fvT[((size_t)hq*DHD+dd)*SEQ + n]) = o;
      }
    }
  }
}

// ---------------------------------------------------------------- S: full column stats (one block per hq,isk)
__global__ void __launch_bounds__(256) colstat_kernel(
    const unsigned short* __restrict__ fq, const unsigned short* __restrict__ fk,
    float* __restrict__ qgp, float* __restrict__ kgp, float* __restrict__ c2A)
{
  int hq = blockIdx.x, isk = blockIdx.y;
  const unsigned short* F = (isk ? fk : fq) + (size_t)hq*SEQ*DHD;
  int t = threadIdx.x, g = t&15, rg = t>>4;
  float acc0=0.f, acc1=0.f, acc2=0.f, acc3=0.f;
  #pragma unroll 4
  for (int i=0;i<32;i++){
    int r = rg + 16*i;
    ushort4v v = *reinterpret_cast<const ushort4v*>(&F[(size_t)r*DHD + g*4]);
    acc0+=bf2f(v[0]); acc1+=bf2f(v[1]); acc2+=bf2f(v[2]); acc3+=bf2f(v[3]);
  }
  __shared__ float sh[16][68];
  sh[rg][g*4+0]=acc0; sh[rg][g*4+1]=acc1; sh[rg][g*4+2]=acc2; sh[rg][g*4+3]=acc3;
  __syncthreads();
  if (t<64){
    float s=0.f;
    #pragma unroll
    for (int r=0;r<16;r++) s += sh[r][t];
    if (isk){
      kgp[hq*64+t]=s;
      float c = s*(1.0f/512.0f);
      #pragma unroll
      for (int m=32;m>0;m>>=1) c += __shfl_xor(c,m,64);
      if (t==0) c2A[hq]=c;
    } else {
      qgp[hq*64+t]=s;
    }
  }
}

// ---------------------------------------------------------------- M1: moments + rowmax + c1 (reg-pipelined K staging)
__global__ void __launch_bounds__(256) score_m1_kernel(
    const unsigned short* __restrict__ fq, const unsigned short* __restrict__ fk,
    const float* __restrict__ aqA, const float* __restrict__ i1qA,
    const float* __restrict__ rskA, const float* __restrict__ i1kA,
    const float* __restrict__ c2A, const float* __restrict__ kgp,
    float* __restrict__ c1A, float* __restrict__ rmaxcA, float* __restrict__ rmaxoA,
    float* __restrict__ momf, double* __restrict__ varp)
{
  // grid (QB, NH, 8): strip slowest -> same-(h,q) blocks land on one XCD
  int q_=blockIdx.x, h=blockIdx.y, strip=blockIdx.z;
  int hq=h*QB+q_, n0=strip*64;
  const unsigned short* Fq=fq+(size_t)hq*SEQ*DHD;
  const unsigned short* Fk=fk+(size_t)hq*SEQ*DHD;
  __shared__ unsigned short KT[128*64];
  __shared__ float rskL[512], i1kL[512];
  __shared__ float red[256];
  __shared__ double dred[256];
  int t=threadIdx.x, w=t>>6, lane=t&63, l16=lane&15, lh=lane>>4;
  int n = n0 + w*16 + l16;
  int srow = t>>3, sq = t&7;
  for (int i=t;i<512;i+=256){ rskL[i]=rskA[hq*SEQ+i]; i1kL[i]=i1kA[hq*SEQ+i]; }
  float c2v = c2A[hq];
  float aqv = aqA[hq*SEQ+n];
  float iq1 = i1qA[hq*SEQ+n];
  short8 qa[2];
  #pragma unroll
  for (int ks=0;ks<2;ks++)
    qa[ks] = *reinterpret_cast<const short8*>(&Fq[(size_t)n*DHD + ks*32 + lh*8]);
  // c1[n] = fq[n] . (kgp/512)
  float c1v = 0.f;
  #pragma unroll
  for (int ks=0;ks<2;ks++){
    const float* bkp = &kgp[hq*64 + ks*32 + lh*8];
    float4 b0 = *reinterpret_cast<const float4*>(bkp);
    float4 b1 = *reinterpret_cast<const float4*>(bkp+4);
    float bb[8] = {b0.x,b0.y,b0.z,b0.w,b1.x,b1.y,b1.z,b1.w};
    #pragma unroll
    for (int i=0;i<8;i++) c1v = fmaf(bf2f((unsigned short)qa[ks][i]), bb[i], c1v);
  }
  c1v *= (1.0f/512.0f);
  c1v += __shfl_xor(c1v,16,64);
  c1v += __shfl_xor(c1v,32,64);
  if (lane<16) c1A[hq*SEQ+n] = c1v;
  float c1x = KCOV*(c1v - aqv*c2v);
  float aqx = KCOV*aqv;
  ushort8v kr[4];
  #pragma unroll
  for (int it=0;it<4;++it)
    kr[it] = *reinterpret_cast<const ushort8v*>(&Fk[(size_t)(srow+it*32)*DHD + sq*8]);
  float sc=0.f,sc2=0.f,so=0.f,so2=0.f,sco=0.f;
  float rc=0.f, ro=0.f, rm=0.f, rmc=-1e30f, rmo=-1e30f;
  for (int mc=0;mc<4;mc++){
    int m0=mc*128;
    __syncthreads();
    #pragma unroll
    for (int it=0;it<4;++it)
      tile_st16(KT, srow+it*32, 128, sq*16, kr[it]);
    __syncthreads();
    if (mc<3){
      #pragma unroll
      for (int it=0;it<4;++it)
        kr[it] = *reinterpret_cast<const ushort8v*>(&Fk[(size_t)(m0+128+srow+it*32)*DHD + sq*8]);
    }
    #pragma unroll
    for (int mh=0;mh<2;mh++){
      int mb = mh*64;
      f32x4 acc[4];
      #pragma unroll
      for (int mf=0;mf<4;mf++) acc[mf]=(f32x4){0.f,0.f,0.f,0.f};
      #pragma unroll
      for (int mf=0;mf<4;mf++){
        #pragma unroll
        for (int ks=0;ks<2;ks++){
          short8 kf = frag_ld(KT, mb+mf*16+l16, 128, lh*16+ks*64);
          acc[mf] = MFMA(kf, qa[ks], acc[mf]);
        }
      }
      #pragma unroll
      for (int mf=0;mf<4;mf++){
        int ml = m0 + mb + mf*16 + lh*4;
        float4 rsk4 = *reinterpret_cast<const float4*>(&rskL[ml]);
        float4 i1k4 = *reinterpret_cast<const float4*>(&i1kL[ml]);
        float rk[4]={rsk4.x,rsk4.y,rsk4.z,rsk4.w};
        float ik[4]={i1k4.x,i1k4.y,i1k4.z,i1k4.w};
        #pragma unroll
        for (int r=0;r<4;r++){
          float S = acc[mf][r];
          float cosv = clampf(S*iq1*ik[r], -0.99f, 0.99f);
          float u = fmaf(KCOV, S, -c1x);
          float covv = fmaf(-aqx, rk[r], u);
          covv = clampf(covv, -10.0f, 10.0f);
          float marg = clampf(0.01f - cosv, 0.0f, 2.0f);
          sc += cosv; sc2 = fmaf(cosv,cosv,sc2);
          so += covv; so2 = fmaf(covv,covv,so2);
          sco = fmaf(cosv,covv,sco);
          rc += cosv; ro += covv; rm += marg;
          rmc = fmaxf(rmc, cosv); rmo = fmaxf(rmo, covv);
        }
      }
    }
  }
  // row reductions across lh (lanes sharing l16)
  rc += __shfl_xor(rc,16,64); rc += __shfl_xor(rc,32,64);
  ro += __shfl_xor(ro,16,64); ro += __shfl_xor(ro,32,64);
  rm += __shfl_xor(rm,16,64); rm += __shfl_xor(rm,32,64);
  rmc = fmaxf(rmc, __shfl_xor(rmc,16,64)); rmc = fmaxf(rmc, __shfl_xor(rmc,32,64));
  rmo = fmaxf(rmo, __shfl_xor(rmo,16,64)); rmo = fmaxf(rmo, __shfl_xor(rmo,32,64));
  if (lane<16){
    rmaxcA[hq*SEQ+n] = rmc;
    rmaxoA[hq*SEQ+n] = rmo;
  }
  double vm=0.0, vm2=0.0, vmc=0.0, vmo=0.0;
  if (lane<16){
    float mm = rm*(1.0f/512.0f);
    vm  = (double)mm;
    vm2 = (double)mm*(double)mm;
    vmc = (double)mm*(double)rc;
    vmo = (double)mm*(double)ro;
  }
  float fs[5]={sc,sc2,so,so2,sco};
  for (int c=0;c<5;c++){
    __syncthreads();
    red[t]=fs[c]; __syncthreads();
    for (int o=128;o>0;o>>=1){ if (t<o) red[t]+=red[t+o]; __syncthreads(); }
    if (t==0) momf[(size_t)(hq*8+strip)*5 + c] = red[0];
  }
  double ds[4]={vm,vm2,vmc,vmo};
  for (int c=0;c<4;c++){
    __syncthreads();
    dred[t]=ds[c]; __syncthreads();
    for (int o=128;o>0;o>>=1){ if (t<o) dred[t]+=dred[t+o]; __syncthreads(); }
    if (t==0) varp[(size_t)(hq*8+strip)*4 + c] = dred[0];
  }
}

// ---------------------------------------------------------------- F: MLP + stds + mix params
__global__ void __launch_bounds__(256) finalize_kernel(
    const float* __restrict__ qgp, const float* __restrict__ kgp,
    const float* __restrict__ wp1w, const float* __restrict__ wp1b,
    const float* __restrict__ wplg, const float* __restrict__ wplb,
    const float* __restrict__ wp2w, const float* __restrict__ wp2b,
    const float* __restrict__ wp3w, const float* __restrict__ wp3b,
    const float* __restrict__ temp,
    const float* __restrict__ momf, const double* __restrict__ varp,
    float* __restrict__ params)
{
  int t = threadIdx.x;
  __shared__ float feats[8][128];
  __shared__ float h1s[8][64];
  __shared__ float h2s[8][32];
  __shared__ float wts[8][3];
  __shared__ double Sh[8][9];
  for (int idx=t; idx<512; idx+=256){
    int h = idx>>6, d = idx&63;
    float s1=0, s2=0;
    for (int qq=0; qq<QB; qq++){ s1 += qgp[(h*QB+qq)*64+d]; s2 += kgp[(h*QB+qq)*64+d]; }
    feats[h][d]    = s1*(1.0f/8192.0f);
    feats[h][64+d] = s2*(1.0f/8192.0f);
  }
  __syncthreads();
  int w = t>>6, j = t&63;
  for (int pp=0; pp<2; pp++){
    int h = w + pp*4;
    float acc = wp1b[j];
    for (int k=0;k<128;k++) acc += feats[h][k]*wp1w[k*64+j];
    float s=acc, s2=acc*acc;
    #pragma unroll
    for (int m=32;m>0;m>>=1){ s+=__shfl_xor(s,m,64); s2+=__shfl_xor(s2,m,64); }
    float mean = s*(1.0f/64.0f);
    float var  = s2*(1.0f/64.0f) - mean*mean;
    float xh = (acc-mean)*rsqrtf(var+1e-5f)*wplg[j] + wplb[j];
    h1s[h][j] = fmaxf(xh, 0.0f);
  }
  __syncthreads();
  {
    int h = t>>5, j2 = t&31;
    float acc = wp2b[j2];
    for (int k=0;k<64;k++) acc += h1s[h][k]*wp2w[k*32+j2];
    h2s[h][j2] = fmaxf(acc, 0.0f);
  }
  __syncthreads();
  if (t<8){
    int h = t;
    float z[3] = {wp3b[0], wp3b[1], wp3b[2]};
    for (int k=0;k<32;k++){
      float hv = h2s[h][k];
      z[0]+=hv*wp3w[k*3]; z[1]+=hv*wp3w[k*3+1]; z[2]+=hv*wp3w[k*3+2];
    }
    float mx = fmaxf(z[0], fmaxf(z[1], z[2]));
    float e0=expf(z[0]-mx), e1=expf(z[1]-mx), e2=expf(z[2]-mx);
    float inv = 1.0f/(e0+e1+e2);
    float l0=e0*inv, l1=e1*inv, l2=e2*inv;
    float tv = temp[0]; tv = fminf(fmaxf(tv, 0.1f), 20.0f);
    float y0=l0/tv, y1=l1/tv, y2=l2/tv;
    float mx2 = fmaxf(y0, fmaxf(y1, y2));
    float f0=expf(y0-mx2), f1=expf(y1-mx2), f2=expf(y2-mx2);
    float inv2 = 1.0f/(f0+f1+f2);
    wts[h][0]=f0*inv2; wts[h][1]=f1*inv2; wts[h][2]=f2*inv2;
  }
  __syncthreads();
  if (t<40){
    int h = t/5, c = t%5;
    double s = 0;
    for (int e=0; e<128; e++) s += (double)momf[(size_t)(h*128+e)*5 + c];
    Sh[h][c] = s;
  }
  __syncthreads();
  if (t<32){
    int h = t>>2, c = t&3;
    double s = 0;
    for (int e=0; e<128; e++) s += varp[(size_t)(h*128+e)*4 + c];
    Sh[h][5+c] = s;
  }
  __syncthreads();
  if (t==0){
    const double Ntot = 33554432.0;
    double T1c=0,T2c=0,T1o=0,T2o=0,T1v=0,T2v=0;
    for (int h=0;h<8;h++){
      T1c+=Sh[h][0]; T2c+=Sh[h][1]; T1o+=Sh[h][2]; T2o+=Sh[h][3];
      T1v+=512.0*Sh[h][5]; T2v+=512.0*Sh[h][6];
    }
    double stdc = sqrt(fmax((T2c - T1c*T1c/Ntot)/(Ntot-1.0), 0.0));
    double stdo = sqrt(fmax((T2o - T1o*T1o/Ntot)/(Ntot-1.0), 0.0));
    double stdv = sqrt(fmax((T2v - T1v*T1v/Ntot)/(Ntot-1.0), 0.0));
    double ah[8], bh[8];
    double Sd1=0, Sd2=0;
    for (int h=0;h<8;h++){
      double a = (double)wts[h][0]/(stdc+1e-8);
      double b = (double)wts[h][1]*0.1/(stdo+1e-8);
      double c = (double)wts[h][2]*0.1/(stdv+1e-8);
      ah[h]=a; bh[h]=b;
      Sd1 += a*Sh[h][0] + b*Sh[h][2] + c*512.0*Sh[h][5];
      Sd2 += a*a*Sh[h][1] + b*b*Sh[h][3] + c*c*512.0*Sh[h][6]
           + 2.0*a*b*Sh[h][4] + 2.0*a*c*Sh[h][7] + 2.0*b*c*Sh[h][8];
    }
    double stdd = sqrt(fmax((Sd2 - Sd1*Sd1/Ntot)/(Ntot-1.0), 0.0));
    double att = 1.0 + 0.5*stdd;
    att = fmin(fmax(att, 0.5), 5.0);
    double scale = 1.0/att;
    for (int h=0;h<8;h++){
      params[h*2+0] = (float)(scale*ah[h]);
      params[h*2+1] = (float)(scale*bh[h]);
    }
  }
}

// ---------------------------------------------------------------- M2: fixed-max softmax + PV (reg-pipelined K/V staging)
__global__ void __launch_bounds__(256) attn_m2_kernel(
    const unsigned short* __restrict__ fq, const unsigned short* __restrict__ fk,
    const unsigned short* __restrict__ fvT,
    const float* __restrict__ aqA, const float* __restrict__ c1A, const float* __restrict__ i1qA,
    const float* __restrict__ rskA, const float* __restrict__ i1kA,
    const float* __restrict__ c2A, const float* __restrict__ params,
    const float* __restrict__ rmaxcA, const float* __restrict__ rmaxoA,
    unsigned short* __restrict__ attn_bf)
{
  // grid (QB, NH, 8): strip slowest -> same-(h,q) blocks land on one XCD
  int q_=blockIdx.x, h=blockIdx.y, strip=blockIdx.z;
  int hq=h*QB+q_, n0=strip*64;
  const unsigned short* Fq=fq+(size_t)hq*SEQ*DHD;
  const unsigned short* Fk=fk+(size_t)hq*SEQ*DHD;
  const unsigned short* FvT=fvT+(size_t)hq*DHD*SEQ;
  __shared__ unsigned short KT[128*64];     // K rows (m) x 64 d
  __shared__ unsigned short VT[64*128];     // [d][m], pitch 256B
  __shared__ unsigned short P[64*64];       // [n][m-half] bf16, pitch 128B
  __shared__ float rskL[512], i1kL[512];
  int t=threadIdx.x, w=t>>6, lane=t&63, l16=lane&15, lh=lane>>4;
  int n = n0 + w*16 + l16;
  int srow = t>>3, sq = t&7;       // K staging: rows srow+32*it
  int vd = t>>4, vc = t&15;        // V staging: d rows vd+... cols vc
  for (int i=t;i<512;i+=256){ rskL[i]=rskA[hq*SEQ+i]; i1kL[i]=i1kA[hq*SEQ+i]; }
  float c2v=c2A[hq];
  float pa=params[h*2], pb=params[h*2+1];
  float aqv = aqA[hq*SEQ+n];
  float c1v = c1A[hq*SEQ+n];
  float iq1 = i1qA[hq*SEQ+n];
  float rmc = rmaxcA[hq*SEQ+n];
  float rmo = rmaxoA[hq*SEQ+n];
  float pbk = pb*KCOV;
  float ra  = pa*iq1;
  float bndc = 0.99f*pa;
  float rowc = -pbk*(c1v - aqv*c2v);
  float r3   = pbk*aqv;
  float Mrow = fmaf(pa, rmc, pb*rmo);
  short8 qa[2];
  #pragma unroll
  for (int ks=0;ks<2;ks++)
    qa[ks] = *reinterpret_cast<const short8*>(&Fq[(size_t)n*DHD + ks*32 + lh*8]);
  short8 ones;
  #pragma unroll
  for (int i=0;i<8;i++) ones[i] = (short)0x3F80;
  f32x4 accO[4];
  #pragma unroll
  for (int j=0;j<4;j++) accO[j]=(f32x4){0.f,0.f,0.f,0.f};
  f32x4 den = (f32x4){0.f,0.f,0.f,0.f};
  int prow = w*16 + l16;
  ushort8v kr[4], vr[4];
  #pragma unroll
  for (int it=0;it<4;++it){
    kr[it] = *reinterpret_cast<const ushort8v*>(&Fk[(size_t)(srow+it*32)*DHD + sq*8]);
    vr[it] = *reinterpret_cast<const ushort8v*>(&FvT[(size_t)(vd+it*16)*SEQ + vc*8]);
  }
  for (int mc=0;mc<4;mc++){
    int m0=mc*128;
    __syncthreads();
    #pragma unroll
    for (int it=0;it<4;++it){
      tile_st16(KT, srow+it*32, 128, sq*16, kr[it]);
      tile_st16(VT, vd+it*16, 256, vc*16, vr[it]);
    }
    __syncthreads();
    if (mc<3){
      #pragma unroll
      for (int it=0;it<4;++it){
        kr[it] = *reinterpret_cast<const ushort8v*>(&Fk[(size_t)(m0+128+srow+it*32)*DHD + sq*8]);
        vr[it] = *reinterpret_cast<const ushort8v*>(&FvT[(size_t)(vd+it*16)*SEQ + m0+128 + vc*8]);
      }
    }
    #pragma unroll
    for (int mh=0;mh<2;mh++){
      int mb = mh*64;
      // QK^T (swapped): acc rows = K rows m, cols = own n
      f32x4 acc[4];
      #pragma unroll
      for (int mf=0;mf<4;mf++) acc[mf]=(f32x4){0.f,0.f,0.f,0.f};
      #pragma unroll
      for (int mf=0;mf<4;mf++){
        #pragma unroll
        for (int ks=0;ks<2;ks++){
          short8 kf = frag_ld(KT, mb+mf*16+l16, 128, lh*16+ks*64);
          acc[mf] = MFMA(kf, qa[ks], acc[mf]);
        }
      }
      // transform + exp(logit - Mrow), write P[n][m] packed
      #pragma unroll
      for (int mf=0;mf<4;mf++){
        int ml = m0 + mb + mf*16 + lh*4;
        float4 rsk4 = *reinterpret_cast<const float4*>(&rskL[ml]);
        float4 i1k4 = *reinterpret_cast<const float4*>(&i1kL[ml]);
        float rk[4]={rsk4.x,rsk4.y,rsk4.z,rsk4.w};
        float ik[4]={i1k4.x,i1k4.y,i1k4.z,i1k4.w};
        #pragma unroll
        for (int r=0;r<4;r++){
          float S = acc[mf][r];
          float tt = S*ra; tt *= ik[r];
          float cc = clampf(tt, -bndc, bndc);
          float u = fmaf(pbk, S, rowc);
          float lin = fmaf(-r3, rk[r], u);
          acc[mf][r] = __expf(cc + lin - Mrow);
        }
        unsigned lo = cvtpk(acc[mf][0], acc[mf][1]);
        unsigned hi = cvtpk(acc[mf][2], acc[mf][3]);
        int pbyte = (mf*32 + lh*8) ^ ((prow&7)<<4);
        *reinterpret_cast<uint2*>(reinterpret_cast<char*>(P) + prow*128 + pbyte)
          = make_uint2(lo, hi);
      }
      // PV + denominator (wave-local P rows; in-wave LDS ordering suffices)
      #pragma unroll
      for (int ks=0;ks<2;ks++){
        short8 pfrag = frag_ld(P, prow, 128, lh*16 + ks*64);
        #pragma unroll
        for (int dcf=0;dcf<4;dcf++){
          short8 vb = frag_ld(VT, dcf*16+l16, 256, mb*2 + ks*64 + lh*16);
          accO[dcf] = MFMA(pfrag, vb, accO[dcf]);
        }
        den = MFMA(pfrag, ones, den);
      }
    }
  }
  // epilogue: normalize, bounce through P, coalesced store
  f32x4 invD;
  #pragma unroll
  for (int r=0;r<4;r++) invD[r] = 1.0f/den[r];
  __syncthreads();
  #pragma unroll
  for (int dcf=0;dcf<4;dcf++){
    #pragma unroll
    for (int r=0;r<4;r++){
      int row = w*16 + lh*4 + r;
      int col = dcf*16 + l16;
      int addr = row*128 + ((col*2) ^ ((row&7)<<4));
      *reinterpret_cast<unsigned short*>(reinterpret_cast<char*>(P) + addr)
        = f2bf(accO[dcf][r]*invD[r]);
    }
  }
  __syncthreads();
  for (int it=0; it<2; ++it){
    int idx = it*256 + t;
    int row = idx>>3, c = idx&7;
    int addr = row*128 + ((c*16) ^ ((row&7)<<4));
    ushort8v vv = *reinterpret_cast<ushort8v*>(reinterpret_cast<char*>(P) + addr);
    *reinterpret_cast<ushort8v*>(
      &attn_bf[(size_t)(q_*SEQ + n0 + row)*DMODEL + h*DHD + c*8]) = vv;
  }
}

// ---------------------------------------------------------------- KO: output projection (reg-pipelined staging)
__global__ void __launch_bounds__(256) out_mfma_kernel(
    const unsigned short* __restrict__ attn_bf, const unsigned short* __restrict__ WoT,
    const float* __restrict__ bias, float* __restrict__ out)
{
  int r0=blockIdx.x*128;
  int c0=blockIdx.y*128;
  __shared__ unsigned short AT[128*64];
  __shared__ unsigned short WT[128*64];
  int t=threadIdx.x, w=t>>6, lane=t&63, l16=lane&15, lh=lane>>4;
  int srow = t>>3, sq = t&7;
  f32x4 acc[4][4];
  #pragma unroll
  for(int i=0;i<4;i++){ for(int j=0;j<4;j++) acc[i][j]=(f32x4){0.f,0.f,0.f,0.f}; }
  ushort8v ar[4], wr[4];
  #pragma unroll
  for (int it=0; it<4; ++it){
    ar[it] = *reinterpret_cast<const ushort8v*>(&attn_bf[(size_t)(r0+srow+it*32)*DMODEL + sq*8]);
    wr[it] = *reinterpret_cast<const ushort8v*>(&WoT[(size_t)(c0+srow+it*32)*DMODEL + sq*8]);
  }
  for (int k0=0;k0<DMODEL;k0+=64){
    __syncthreads();
    #pragma unroll
    for (int it=0; it<4; ++it){
      tile_st16(AT, srow+it*32, 128, sq*16, ar[it]);
      tile_st16(WT, srow+it*32, 128, sq*16, wr[it]);
    }
    __syncthreads();
    if (k0+64 < DMODEL){
      #pragma unroll
      for (int it=0; it<4; ++it){
        ar[it] = *reinterpret_cast<const ushort8v*>(&attn_bf[(size_t)(r0+srow+it*32)*DMODEL + k0+64 + sq*8]);
        wr[it] = *reinterpret_cast<const ushort8v*>(&WoT[(size_t)(c0+srow+it*32)*DMODEL + k0+64 + sq*8]);
      }
    }
    int nr=(w&1)*64, mr=(w>>1)*64;
    #pragma unroll
    for (int ks=0; ks<2; ++ks){
      int kb = lh*16 + ks*64;
      short8 a[4], b[4];
      #pragma unroll
      for (int i=0;i<4;i++) a[i] = frag_ld(WT, nr+i*16+l16, 128, kb);
      #pragma unroll
      for (int j=0;j<4;j++) b[j] = frag_ld(AT, mr+j*16+l16, 128, kb);
      #pragma unroll
      for (int i=0;i<4;i++){
        #pragma unroll
        for (int j=0;j<4;j++) acc[i][j]=MFMA(a[i],b[j],acc[i][j]);
      }
    }
  }
  #pragma unroll
  for (int i=0;i<4;i++){
    int nb = c0+(w&1)*64+i*16+lh*4;
    float4 b4 = *reinterpret_cast<const float4*>(&bias[nb]);
    #pragma unroll
    for (int j=0;j<4;j++){
      int mg = r0+(w>>1)*64+j*16+l16;
      f32x4 o = acc[i][j];
      o[0]+=b4.x; o[1]+=b4.y; o[2]+=b4.z; o[3]+=b4.w;
      *reinterpret_cast<f32x4*>(&out[(size_t)mg*DMODEL + nb]) = o;
    }
  }
}

// ----------------------------------------------------------------
extern "C" void kernel_launch(void* const* d_in, const int* in_sizes, int n_in,
                              void* d_out, int out_size, void* d_ws, size_t ws_size,
                              hipStream_t stream)
{
  (void)in_sizes; (void)n_in; (void)out_size; (void)ws_size;
  const float* q     = (const float*)d_in[0];
  const float* k     = (const float*)d_in[1];
  const float* v     = (const float*)d_in[2];
  const float* ln_g  = (const float*)d_in[3];
  const float* ln_b  = (const float*)d_in[4];
  const float* W_in  = (const float*)d_in[5];
  const float* wp1w  = (const float*)d_in[6];
  const float* wp1b  = (const float*)d_in[7];
  const float* wplg  = (const float*)d_in[8];
  const float* wplb  = (const float*)d_in[9];
  const float* wp2w  = (const float*)d_in[10];
  const float* wp2b  = (const float*)d_in[11];
  const float* wp3w  = (const float*)d_in[12];
  const float* wp3b  = (const float*)d_in[13];
  const float* temp  = (const float*)d_in[14];
  const float* W_out = (const float*)d_in[15];
  const float* b_out = (const float*)d_in[16];
  float* out = (float*)d_out;

  char* wsb = (char*)d_ws;
  size_t off = 0;
  auto alloc = [&](size_t bytes)->char*{
    char* p = wsb + off; off += (bytes + 255) & ~(size_t)255; return p;
  };
  unsigned short* xln    = (unsigned short*)alloc((size_t)3*NROWS*DMODEL*2);
  unsigned short* fq_b   = (unsigned short*)alloc((size_t)NHQ*SEQ*DHD*2);
  unsigned short* fk_b   = (unsigned short*)alloc((size_t)NHQ*SEQ*DHD*2);
  unsigned short* fvT_b  = (unsigned short*)alloc((size_t)NHQ*SEQ*DHD*2);
  unsigned short* attn_b = (unsigned short*)alloc((size_t)NROWS*DMODEL*2);
  unsigned short* WiT    = (unsigned short*)alloc((size_t)DMODEL*DMODEL*2);
  unsigned short* WoT    = (unsigned short*)alloc((size_t)DMODEL*DMODEL*2);
  float* aqA    = (float*)alloc(NHQ*SEQ*4);
  float* c1A    = (float*)alloc(NHQ*SEQ*4);
  float* i1qA   = (float*)alloc(NHQ*SEQ*4);
  float* rskA   = (float*)alloc(NHQ*SEQ*4);
  float* i1kA   = (float*)alloc(NHQ*SEQ*4);
  float* rmaxcA = (float*)alloc(NHQ*SEQ*4);
  float* rmaxoA = (float*)alloc(NHQ*SEQ*4);
  float* c2A    = (float*)alloc(NHQ*4);
  float* qgp    = (float*)alloc(NHQ*64*4);
  float* kgp    = (float*)alloc(NHQ*64*4);
  float* momf   = (float*)alloc((size_t)NHQ*8*5*4);
  double* varp  = (double*)alloc((size_t)NHQ*8*4*8);
  float* params = (float*)alloc(64);

  prep_kernel<<<6272, 256, 0, stream>>>(q, k, v, ln_g, ln_b, W_in, W_out, xln, WiT, WoT);
  proj_mfma_kernel<<<dim3(64,4,3), 256, 0, stream>>>(xln, WiT, fq_b, fk_b, fvT_b,
                                                     aqA, i1qA, rskA, i1kA);
  colstat_kernel<<<dim3(NHQ, 2), 256, 0, stream>>>(fq_b, fk_b, qgp, kgp, c2A);
  score_m1_kernel<<<dim3(QB, NH, 8), 256, 0, stream>>>(fq_b, fk_b, aqA, i1qA, rskA, i1kA,
                                                       c2A, kgp, c1A, rmaxcA, rmaxoA, momf, varp);
  finalize_kernel<<<1, 256, 0, stream>>>(qgp, kgp, wp1w, wp1b, wplg, wplb, wp2w, wp2b,
                                         wp3w, wp3b, temp, momf, varp, params);
  attn_m2_kernel<<<dim3(QB, NH, 8), 256, 0, stream>>>(fq_b, fk_b, fvT_b, aqA, c1A, i1qA,
                                                      rskA, i1kA, c2A, params, rmaxcA, rmaxoA, attn_b);
  out_mfma_kernel<<<dim3(64,4), 256, 0, stream>>>(attn_b, WoT, b_out, out);
}